// Round 17
// baseline (423.460 us; speedup 1.0000x reference)
//
#include <hip/hip_runtime.h>
#include <math.h>

// Geometry: C=96, NHEAD=8, dh=12 (pad 16), D,H,W=24,96,96; wavelet grid 12,48,48
// windows 4x8x8=256, Lq=864 (54 m-tiles of 16), Lk=108 (pad 112/128)
// pi-permutation on k (and pi' on d) makes PV/out-proj B-fragments lane-local:
//   pi(k):  p = (nt>>1)*32 + gk*8 + (nt&1)*4 + r   where k = 16nt + 4gk + r
//   pi'(h,d): p = (h>>1)*32 + (d>>2)*8 + (h&1)*4 + (d&3)
// FROZEN: k_att4 structure (r12/r16 proven). >2 waves/SIMD, LDS re-layout, setprio => fails.
// Only register-level load batching is proven safe on k_att4 (r10 +37%).

using short8 = __attribute__((ext_vector_type(8))) short;
using f32x4  = __attribute__((ext_vector_type(4))) float;

__device__ __forceinline__ unsigned short f2bf(float f) {
  unsigned u = __builtin_bit_cast(unsigned, f);
  unsigned r = u + 0x7fffu + ((u >> 16) & 1u);
  return (unsigned short)(r >> 16);
}
__device__ __forceinline__ unsigned cvtpk(float a, float b) {
  unsigned r;
  asm("v_cvt_pk_bf16_f32 %0, %1, %2" : "=v"(r) : "v"(a), "v"(b));
  return r;
}
__device__ __forceinline__ short8 mk8(unsigned a, unsigned b, unsigned c, unsigned d) {
  union { unsigned u[4]; short8 s; } x;
  x.u[0] = a; x.u[1] = b; x.u[2] = c; x.u[3] = d;
  return x.s;
}

// workspace byte offsets (high-water ~37.2 MB; round-1 proved >=53.2 MB usable)
#define OFFB_TAB   0u          // 31104 f32
#define OFFB_GSUM  124416u
#define OFFB_GLO   124800u
#define OFFB_XM    125184u     // 2654208 f32
#define OFFB_LOW   10742016u   // 2654208 f32
#define OFFB_WQ    21358848u   // 9216 bf16
#define OFFB_WK    21377280u
#define OFFB_WV    21395712u
#define OFFB_KP    21414144u   // kp2[(nw*8+h)*112+kk][16]: 7340032 B (pads zero)
#define OFFB_VT    28754176u   // vtp[(nw*8+h)*16+d][128 pi-cols]: 8388608 B (pads zero)
#define OFFB_WOP   37142784u   // wop2[96][128 pi'-cols]: 24576 B (pads zero)
#define OFFB_WG1   37167360u   // 9216 bf16 gate W1
#define OFFB_WG2   37185792u   // 9216 bf16 gate W2
#define MEMSET_OFF 21414144u
#define MEMSET_LEN 15753216u   // kp2 + vtp + wop2

// ---------------- pos tables: tab[p*96+c], p in [0,324) ----------------
__global__ void k_pos(const float* __restrict__ pos_w, float* __restrict__ tab) {
  int idx = blockIdx.x * 256 + threadIdx.x;
  if (idx >= 324 * 96) return;
  int c = idx % 96, p = idx / 96;
  int Dm, fo, pl;
  if (p < 24)       { Dm = 24; fo = 0;   pl = p; }
  else if (p < 120) { Dm = 96; fo = 64;  pl = p - 24; }
  else if (p < 216) { Dm = 96; fo = 128; pl = p - 120; }
  else if (p < 228) { Dm = 12; fo = 0;   pl = p - 216; }
  else if (p < 276) { Dm = 48; fo = 64;  pl = p - 228; }
  else              { Dm = 48; fo = 128; pl = p - 276; }
  float pos = (float)pl / ((float)(Dm - 1) + 1e-6f) * 6.2831853071795864769f;
  float acc = 0.f;
  for (int i = 0; i < 32; ++i) {
    float inv = __expf((float)i * -0.2878231366242558f);  // 10000^(-i/32)
    float a = pos * inv;
    acc += sinf(a) * pos_w[c * 192 + fo + 2 * i] + cosf(a) * pos_w[c * 192 + fo + 2 * i + 1];
  }
  tab[p * 96 + c] = acc;
}

// ---------------- weight prep: f32 -> bf16 ----------------
__global__ void k_wprep(const float* __restrict__ in_w, const float* __restrict__ out_w,
                        const float* __restrict__ l_w1, const float* __restrict__ l_w2,
                        unsigned short* __restrict__ wq, unsigned short* __restrict__ wk,
                        unsigned short* __restrict__ wv, unsigned short* __restrict__ wop2,
                        unsigned short* __restrict__ wg1, unsigned short* __restrict__ wg2) {
  int i = blockIdx.x * 256 + threadIdx.x;
  if (i < 9216) {
    wq[i] = f2bf(in_w[i]);
    wk[i] = f2bf(in_w[9216 + i]);
    wv[i] = f2bf(in_w[18432 + i]);
    wg1[i] = f2bf(l_w1[i]);
    wg2[i] = f2bf(l_w2[i]);
    int co = i / 96, ci = i % 96;
    int hh = ci / 12, dd = ci % 12;
    wop2[co * 128 + (hh >> 1) * 32 + (dd >> 2) * 8 + (hh & 1) * 4 + (dd & 3)] = f2bf(out_w[i]);
  }
}

// ---------------- wavelet: low = s3*sum8, xm = 2sqrt2*x(odd,odd,odd) ----------------
__global__ void k_wav(const float* __restrict__ mem, float* __restrict__ xm_g,
                      float* __restrict__ low_g, float* __restrict__ gsum) {
  __shared__ float sxm[96][49];
  __shared__ float slow[96][49];
  int dk = blockIdx.x / 48, hk = blockIdx.x % 48;
  int tid = threadIdx.x;
  for (int idx = tid; idx < 96 * 48; idx += 256) {
    int wk = idx % 48, c = idx / 48;
    const float* p = mem + (((size_t)c * 24 + 2 * dk) * 96 + 2 * hk) * 96 + 2 * wk;
    float s = p[0] + p[1] + p[96] + p[97];
    const float* p2 = p + 96 * 96;
    float x111 = p2[97];
    s += p2[0] + p2[1] + p2[96] + x111;
    sxm[c][wk] = 2.8284271247461903f * x111;
    slow[c][wk] = 0.35355339059327373f * s;
  }
  __syncthreads();
  int n0 = (dk * 48 + hk) * 48;
  for (int idx = tid; idx < 96 * 48; idx += 256) {
    int c = idx % 96, t = idx / 96;
    xm_g[(size_t)(n0 + t) * 96 + c] = sxm[c][t];
    low_g[(size_t)(n0 + t) * 96 + c] = slow[c][t];
  }
  if (tid < 96) {
    float a = 0.f;
    for (int t = 0; t < 48; ++t) a += sxm[tid][t];
    atomicAdd(&gsum[tid], a);
  }
}

// ---------------- global gate MLP (1 block) ----------------
__global__ void k_glo(const float* __restrict__ gsum, const float* __restrict__ g_w1,
                      const float* __restrict__ g_b1, const float* __restrict__ g_w2,
                      const float* __restrict__ g_b2, float* __restrict__ glo) {
  __shared__ float sg[96], sh[96];
  int t = threadIdx.x;
  if (t < 96) sg[t] = gsum[t] * (1.f / 27648.f);
  __syncthreads();
  if (t < 96) {
    float a = g_b1[t];
    for (int i = 0; i < 96; ++i) a += sg[i] * g_w1[t * 96 + i];
    sh[t] = fmaxf(a, 0.f);
  }
  __syncthreads();
  if (t < 96) {
    float a = g_b2[t];
    for (int i = 0; i < 96; ++i) a += sh[i] * g_w2[t * 96 + i];
    glo[t] = a;
  }
}

// ---------------- fused gate MLP + K/V projection (r16 proven) ----------------
__global__ __launch_bounds__(256) void k_gkv(
    const float* __restrict__ xm_g, const float* __restrict__ low_g,
    const float* __restrict__ tab,
    const unsigned short* __restrict__ wg1, const unsigned short* __restrict__ wg2,
    const float* __restrict__ l_b1, const float* __restrict__ l_b2,
    const float* __restrict__ glo,
    const unsigned short* __restrict__ wk, const unsigned short* __restrict__ wv,
    const float* __restrict__ in_b,
    unsigned short* __restrict__ kp2, unsigned short* __restrict__ vtp) {
  __shared__ unsigned short sXin[112 * 104];
  __shared__ unsigned short sH[112 * 104];
  __shared__ unsigned short sKin[112 * 104];
  __shared__ unsigned short sVin[112 * 104];
  __shared__ unsigned short sVt[4 * 96 * 18];
  int tid = threadIdx.x, nw = blockIdx.x;
  int dg = nw >> 6, hg = (nw >> 3) & 7, wg_ = nw & 7;
  for (int idx = tid; idx < 112 * 48; idx += 256) {
    int row = idx % 112, cop = idx / 112;
    int co = cop * 2;
    unsigned pk = 0;
    if (row < 108) {
      int ld = row / 36, lh = (row / 6) % 6, lw = row % 6;
      int n = ((dg * 3 + ld) * 48 + hg * 6 + lh) * 48 + wg_ * 6 + lw;
      float f0 = xm_g[(size_t)n * 96 + co], f1 = xm_g[(size_t)n * 96 + co + 1];
      pk = (unsigned)f2bf(f0) | ((unsigned)f2bf(f1) << 16);
    } else {
      *(unsigned*)(&sKin[row * 104 + co]) = 0;
      *(unsigned*)(&sVin[row * 104 + co]) = 0;
    }
    *(unsigned*)(&sXin[row * 104 + co]) = pk;
  }
  __syncthreads();
  int wave = tid >> 6, lane = tid & 63, l15 = lane & 15, g = lane >> 4;
  for (int mtk = wave; mtk < 7; mtk += 4) {
    f32x4 D[6];
    #pragma unroll
    for (int nt = 0; nt < 6; ++nt) D[nt] = f32x4{0.f, 0.f, 0.f, 0.f};
    #pragma unroll
    for (int ks = 0; ks < 3; ++ks) {
      short8 a = *(const short8*)(&sXin[(mtk * 16 + l15) * 104 + ks * 32 + g * 8]);
      #pragma unroll
      for (int nt = 0; nt < 6; ++nt) {
        short8 b = *(const short8*)(&wg1[(nt * 16 + l15) * 96 + ks * 32 + g * 8]);
        D[nt] = __builtin_amdgcn_mfma_f32_16x16x32_bf16(a, b, D[nt], 0, 0, 0);
      }
    }
    #pragma unroll
    for (int nt = 0; nt < 6; ++nt) {
      int co = nt * 16 + l15;
      float b1v = l_b1[co];
      #pragma unroll
      for (int r = 0; r < 4; ++r) {
        float h = fmaxf(D[nt][r] + b1v, 0.f);
        float h2 = __shfl_xor(h, 1);
        if (!(l15 & 1)) {
          int row = mtk * 16 + g * 4 + r;
          *(unsigned*)(&sH[row * 104 + co]) = (unsigned)f2bf(h) | ((unsigned)f2bf(h2) << 16);
        }
      }
    }
    asm volatile("s_waitcnt lgkmcnt(0)" ::: "memory");
    f32x4 A[6];
    #pragma unroll
    for (int nt = 0; nt < 6; ++nt) A[nt] = f32x4{0.f, 0.f, 0.f, 0.f};
    #pragma unroll
    for (int ks = 0; ks < 3; ++ks) {
      short8 a = *(const short8*)(&sH[(mtk * 16 + l15) * 104 + ks * 32 + g * 8]);
      #pragma unroll
      for (int nt = 0; nt < 6; ++nt) {
        short8 b = *(const short8*)(&wg2[(nt * 16 + l15) * 96 + ks * 32 + g * 8]);
        A[nt] = __builtin_amdgcn_mfma_f32_16x16x32_bf16(a, b, A[nt], 0, 0, 0);
      }
    }
    #pragma unroll
    for (int nt = 0; nt < 6; ++nt) {
      int co = nt * 16 + l15;
      float gb = l_b2[co] + glo[co];
      #pragma unroll
      for (int r = 0; r < 4; ++r) {
        int row = mtk * 16 + g * 4 + r;
        float fre = 0.f;
        if (row < 108) {
          int ld = row / 36, lh = (row / 6) % 6, lw = row % 6;
          int n = ((dg * 3 + ld) * 48 + hg * 6 + lh) * 48 + wg_ * 6 + lw;
          size_t off = (size_t)n * 96 + co;
          float wgv = 1.f / (1.f + __expf(-(A[nt][r] + gb)));
          float xv = xm_g[off], lo = low_g[off];
          fre = wgv * (xv - lo) + lo;
        }
        float fre2 = __shfl_xor(fre, 1);
        if (!(l15 & 1) && row < 108) {
          *(unsigned*)(&sVin[row * 104 + co]) = (unsigned)f2bf(fre) | ((unsigned)f2bf(fre2) << 16);
          int ld = row / 36, lh = (row / 6) % 6, lw = row % 6;
          int dk = dg * 3 + ld, hk = hg * 6 + lh, wkk = wg_ * 6 + lw;
          float p0 = tab[20736 + dk * 96 + co] + tab[21888 + hk * 96 + co] + tab[26496 + wkk * 96 + co];
          float p1 = tab[20736 + dk * 96 + co + 1] + tab[21888 + hk * 96 + co + 1] + tab[26496 + wkk * 96 + co + 1];
          *(unsigned*)(&sKin[row * 104 + co]) = (unsigned)f2bf(fre + p0) | ((unsigned)f2bf(fre2 + p1) << 16);
        }
      }
    }
    asm volatile("s_waitcnt lgkmcnt(0)" ::: "memory");
    f32x4 DK[6], DV[6];
    #pragma unroll
    for (int nt = 0; nt < 6; ++nt) { DK[nt] = f32x4{0.f,0.f,0.f,0.f}; DV[nt] = f32x4{0.f,0.f,0.f,0.f}; }
    #pragma unroll
    for (int ks = 0; ks < 3; ++ks) {
      short8 ak = *(const short8*)(&sKin[(mtk * 16 + l15) * 104 + ks * 32 + g * 8]);
      short8 av = *(const short8*)(&sVin[(mtk * 16 + l15) * 104 + ks * 32 + g * 8]);
      #pragma unroll
      for (int nt = 0; nt < 6; ++nt) {
        short8 bk = *(const short8*)(&wk[(nt * 16 + l15) * 96 + ks * 32 + g * 8]);
        short8 bv = *(const short8*)(&wv[(nt * 16 + l15) * 96 + ks * 32 + g * 8]);
        DK[nt] = __builtin_amdgcn_mfma_f32_16x16x32_bf16(ak, bk, DK[nt], 0, 0, 0);
        DV[nt] = __builtin_amdgcn_mfma_f32_16x16x32_bf16(av, bv, DV[nt], 0, 0, 0);
      }
    }
    #pragma unroll
    for (int nt = 0; nt < 6; ++nt) {
      int co = nt * 16 + l15;
      float bk_ = in_b[96 + co], bv_ = in_b[192 + co];
      #pragma unroll
      for (int r = 0; r < 4; ++r) {
        int row = g * 4 + r;
        int kk = mtk * 16 + row;
        float vk = DK[nt][r] + bk_;
        float vk2 = __shfl_xor(vk, 1);
        if (!(l15 & 1) && kk < 108) {
          unsigned pk = (unsigned)f2bf(vk) | ((unsigned)f2bf(vk2) << 16);
          *(unsigned*)(&kp2[((size_t)(nw * 8 + co / 12) * 112 + kk) * 16 + co % 12]) = pk;
        }
        float vv = DV[nt][r] + bv_;
        sVt[wave * 1728 + co * 18 + row] = f2bf(vv);
      }
    }
    asm volatile("s_waitcnt lgkmcnt(0)" ::: "memory");
    int cnt = (mtk == 6) ? 12 : 16;
    for (int co = lane; co < 96; co += 64) {
      int hh = co / 12, dd = co % 12;
      size_t vrowb = ((size_t)(nw * 8 + hh) * 16 + dd) * 128;
      for (int kk2 = 0; kk2 < cnt; kk2 += 2) {
        unsigned v = *(const unsigned*)(&sVt[wave * 1728 + co * 18 + kk2]);
        int p = (mtk >> 1) * 32 + (kk2 >> 2) * 8 + (mtk & 1) * 4 + (kk2 & 3);
        *(unsigned*)(&vtp[vrowb + p]) = v;
      }
    }
  }
}

// ---------------- paired heads: both heads' loads batched; per-head math = r12 verbatim ----------------
__device__ __forceinline__ void proc_head2(
    const unsigned short* qtile, const unsigned short* kb, const unsigned short* vb,
    int h0, int lane, int l15, int g, f32x4& oAr, f32x4& oBr) {
  short8 bqA = short8{0,0,0,0,0,0,0,0}, bqB = short8{0,0,0,0,0,0,0,0};
  if (lane < 32) {
    bqA = *(const short8*)(&qtile[l15 * 136 + h0 * 16 + g * 8]);
    bqB = *(const short8*)(&qtile[l15 * 136 + (h0 + 1) * 16 + g * 8]);
  }
  short8 akA[7], akB[7];
  #pragma unroll
  for (int nt = 0; nt < 7; ++nt) {
    akA[nt] = short8{0,0,0,0,0,0,0,0};
    akB[nt] = short8{0,0,0,0,0,0,0,0};
    if (lane < 32) {
      akA[nt] = *(const short8*)(&kb[((size_t)h0 * 112 + nt * 16 + l15) * 16 + g * 8]);
      akB[nt] = *(const short8*)(&kb[((size_t)(h0 + 1) * 112 + nt * 16 + l15) * 16 + g * 8]);
    }
  }
  f32x4 SA[7], SB[7];
  #pragma unroll
  for (int nt = 0; nt < 7; ++nt) {
    SA[nt] = __builtin_amdgcn_mfma_f32_16x16x32_bf16(akA[nt], bqA, f32x4{0.f,0.f,0.f,0.f}, 0, 0, 0);
    SB[nt] = __builtin_amdgcn_mfma_f32_16x16x32_bf16(akB[nt], bqB, f32x4{0.f,0.f,0.f,0.f}, 0, 0, 0);
  }
  float mxA = -3e38f, mxB = -3e38f;
  #pragma unroll
  for (int nt = 0; nt < 6; ++nt) {
    #pragma unroll
    for (int r = 0; r < 4; ++r) { mxA = fmaxf(mxA, SA[nt][r]); mxB = fmaxf(mxB, SB[nt][r]); }
  }
  if (g < 3) {
    #pragma unroll
    for (int r = 0; r < 4; ++r) { mxA = fmaxf(mxA, SA[6][r]); mxB = fmaxf(mxB, SB[6][r]); }
  }
  mxA = fmaxf(mxA, __shfl_xor(mxA, 16));
  mxB = fmaxf(mxB, __shfl_xor(mxB, 16));
  mxA = fmaxf(mxA, __shfl_xor(mxA, 32));
  mxB = fmaxf(mxB, __shfl_xor(mxB, 32));
  float sumA = 0.f, sumB = 0.f;
  #pragma unroll
  for (int nt = 0; nt < 7; ++nt) {
    #pragma unroll
    for (int r = 0; r < 4; ++r) {
      float eA = __expf(SA[nt][r] - mxA);
      float eB = __expf(SB[nt][r] - mxB);
      if (nt == 6 && g == 3) { eA = 0.f; eB = 0.f; }
      SA[nt][r] = eA; sumA += eA;
      SB[nt][r] = eB; sumB += eB;
    }
  }
  sumA += __shfl_xor(sumA, 16);
  sumB += __shfl_xor(sumB, 16);
  sumA += __shfl_xor(sumA, 32);
  sumB += __shfl_xor(sumB, 32);
  float invA = 1.f / sumA, invB = 1.f / sumB;
  short8 avA[4], avB[4];
  #pragma unroll
  for (int ks = 0; ks < 4; ++ks) {
    avA[ks] = *(const short8*)(&vb[((size_t)h0 * 16 + l15) * 128 + ks * 32 + g * 8]);
    avB[ks] = *(const short8*)(&vb[((size_t)(h0 + 1) * 16 + l15) * 128 + ks * 32 + g * 8]);
  }
  f32x4 oA = f32x4{0.f, 0.f, 0.f, 0.f}, oB = f32x4{0.f, 0.f, 0.f, 0.f};
  #pragma unroll
  for (int ks = 0; ks < 4; ++ks) {
    unsigned wA0 = cvtpk(SA[2 * ks][0], SA[2 * ks][1]);
    unsigned wA1 = cvtpk(SA[2 * ks][2], SA[2 * ks][3]);
    unsigned wB0 = cvtpk(SB[2 * ks][0], SB[2 * ks][1]);
    unsigned wB1 = cvtpk(SB[2 * ks][2], SB[2 * ks][3]);
    unsigned wA2 = 0, wA3 = 0, wB2 = 0, wB3 = 0;
    if (ks < 3) {
      wA2 = cvtpk(SA[2 * ks + 1][0], SA[2 * ks + 1][1]);
      wA3 = cvtpk(SA[2 * ks + 1][2], SA[2 * ks + 1][3]);
      wB2 = cvtpk(SB[2 * ks + 1][0], SB[2 * ks + 1][1]);
      wB3 = cvtpk(SB[2 * ks + 1][2], SB[2 * ks + 1][3]);
    }
    short8 paA = mk8(wA0, wA1, wA2, wA3);
    short8 paB = mk8(wB0, wB1, wB2, wB3);
    oA = __builtin_amdgcn_mfma_f32_16x16x32_bf16(avA[ks], paA, oA, 0, 0, 0);
    oB = __builtin_amdgcn_mfma_f32_16x16x32_bf16(avB[ks], paB, oB, 0, 0, 0);
  }
  oA[0] *= invA; oA[1] *= invA; oA[2] *= invA; oA[3] *= invA;
  oB[0] *= invB; oB[1] *= invB; oB[2] *= invB; oB[3] *= invB;
  oAr = oA; oBr = oB;
}

// ---------------- fused attention v4f (r12 structure; paired-head load batching) ----------------
__global__ __launch_bounds__(256, 2) void k_att4(
    const float* __restrict__ query, const float* __restrict__ tab,
    const unsigned short* __restrict__ kp2, const unsigned short* __restrict__ vtp,
    const unsigned short* __restrict__ wq, const unsigned short* __restrict__ wop2,
    const float* __restrict__ in_b, const float* __restrict__ out_b,
    const float* __restrict__ ln_w, const float* __restrict__ ln_b,
    float* __restrict__ out) {
  __shared__ __align__(16) unsigned char smem[34816];
  int tid = threadIdx.x;
  int nw = blockIdx.x, part = blockIdx.y;
  int dg = nw >> 6, hg = (nw >> 3) & 7, wg = nw & 7;
  int wave = tid >> 6, lane = tid & 63, l15 = lane & 15, g = lane >> 4;
  unsigned char* wbase = smem + wave * 8704;
  unsigned short* qtile = (unsigned short*)wbase;   // [16][136] head-padded scaled Q
  unsigned short* sPq   = qtile + 2176;             // [16][136] qin staging
  int wid = part * 4 + wave;                        // [0,16)

  for (int c = lane; c < 544; c += 64)
    *(int4*)(wbase + c * 16) = int4{0, 0, 0, 0};
  asm volatile("s_waitcnt lgkmcnt(0)" ::: "memory");

  const float scale = 0.28867513459481287f;  // 1/sqrt(12), folded into q
  float biasq[6];
  #pragma unroll
  for (int nt = 0; nt < 6; ++nt) biasq[nt] = in_b[nt * 16 + l15];
  const unsigned short* kb = kp2 + (size_t)nw * 8 * 112 * 16;
  const unsigned short* vb = vtp + (size_t)nw * 8 * 16 * 128;

  for (int mt = wid; mt < 54; mt += 16) {
    for (int c = lane; c < 16 * 48; c += 64) {
      int row = c & 15, cop = c >> 4;
      int co = cop * 2;
      int l = mt * 16 + row;
      int ld = l / 144, lh = (l / 12) % 12, lw = l % 12;
      int d = dg * 6 + ld, h = hg * 12 + lh, w = wg * 12 + lw;
      size_t qoff = (((size_t)co * 24 + d) * 96 + h) * 96 + w;
      float v0 = query[qoff] + tab[d * 96 + co] + tab[2304 + h * 96 + co] + tab[11520 + w * 96 + co];
      float v1 = query[qoff + 221184] + tab[d * 96 + co + 1] + tab[2304 + h * 96 + co + 1] + tab[11520 + w * 96 + co + 1];
      *(unsigned*)(&sPq[row * 136 + co]) = (unsigned)f2bf(v0) | ((unsigned)f2bf(v1) << 16);
    }
    asm volatile("s_waitcnt lgkmcnt(0)" ::: "memory");
    {
      f32x4 QD[6];
      #pragma unroll
      for (int nt = 0; nt < 6; ++nt) QD[nt] = f32x4{0.f, 0.f, 0.f, 0.f};
      #pragma unroll
      for (int ks = 0; ks < 3; ++ks) {
        short8 a = *(const short8*)(&sPq[l15 * 136 + ks * 32 + g * 8]);
        #pragma unroll
        for (int nt = 0; nt < 6; ++nt) {
          short8 bw = *(const short8*)(&wq[(nt * 16 + l15) * 96 + ks * 32 + g * 8]);
          QD[nt] = __builtin_amdgcn_mfma_f32_16x16x32_bf16(a, bw, QD[nt], 0, 0, 0);
        }
      }
      #pragma unroll
      for (int nt = 0; nt < 6; ++nt) {
        int co = nt * 16 + l15;
        #pragma unroll
        for (int r = 0; r < 4; ++r) {
          float v = (QD[nt][r] + biasq[nt]) * scale;
          float v2 = __shfl_xor(v, 1);
          if (!(l15 & 1)) {
            int row = g * 4 + r;
            unsigned pk = (unsigned)f2bf(v) | ((unsigned)f2bf(v2) << 16);
            *(unsigned*)(&qtile[row * 136 + (co / 12) * 16 + co % 12]) = pk;
          }
        }
      }
    }
    asm volatile("s_waitcnt lgkmcnt(0)" ::: "memory");
    f32x4 R[6];
    #pragma unroll
    for (int nt = 0; nt < 6; ++nt) R[nt] = f32x4{0.f, 0.f, 0.f, 0.f};
    #pragma unroll
    for (int hp = 0; hp < 4; ++hp) {
      f32x4 oA, oB;
      proc_head2(qtile, kb, vb, 2 * hp, lane, l15, g, oA, oB);
      short8 pb = mk8(cvtpk(oA[0], oA[1]), cvtpk(oA[2], oA[3]),
                      cvtpk(oB[0], oB[1]), cvtpk(oB[2], oB[3]));
      #pragma unroll
      for (int nt = 0; nt < 6; ++nt) {
        short8 aw = *(const short8*)(&wop2[(nt * 16 + l15) * 128 + hp * 32 + g * 8]);
        R[nt] = __builtin_amdgcn_mfma_f32_16x16x32_bf16(aw, pb, R[nt], 0, 0, 0);
      }
    }
    {
      int l = mt * 16 + l15;
      int ld = l / 144, lh = (l / 12) % 12, lw = l % 12;
      int d = dg * 6 + ld, h_ = hg * 12 + lh, w_ = wg * 12 + lw;
      size_t sp = ((size_t)d * 96 + h_) * 96 + w_;
      float s = 0.f, s2 = 0.f;
      #pragma unroll
      for (int nt = 0; nt < 6; ++nt) {
        #pragma unroll
        for (int r = 0; r < 4; ++r) {
          int co = nt * 16 + 4 * g + r;
          float v = R[nt][r] + out_b[co] + query[(size_t)co * 221184 + sp];
          R[nt][r] = v;
          s += v; s2 += v * v;
        }
      }
      s += __shfl_xor(s, 16); s2 += __shfl_xor(s2, 16);
      s += __shfl_xor(s, 32); s2 += __shfl_xor(s2, 32);
      float mu = s * (1.f / 96.f);
      float var = s2 * (1.f / 96.f) - mu * mu;
      float rstd = rsqrtf(var + 1e-5f);
      #pragma unroll
      for (int nt = 0; nt < 6; ++nt) {
        #pragma unroll
        for (int r = 0; r < 4; ++r) {
          int co = nt * 16 + 4 * g + r;
          out[(size_t)co * 221184 + sp] = (R[nt][r] - mu) * rstd * ln_w[co] + ln_b[co];
        }
      }
    }
  } // m-tiles
}

extern "C" void kernel_launch(void* const* d_in, const int* in_sizes, int n_in,
                              void* d_out, int out_size, void* d_ws, size_t ws_size,
                              hipStream_t stream) {
  const float* query = (const float*)d_in[0];
  const float* mem   = (const float*)d_in[1];
  const float* pos_w = (const float*)d_in[2];
  const float* l_w1  = (const float*)d_in[3];
  const float* l_b1  = (const float*)d_in[4];
  const float* l_w2  = (const float*)d_in[5];
  const float* l_b2  = (const float*)d_in[6];
  const float* g_w1  = (const float*)d_in[7];
  const float* g_b1  = (const float*)d_in[8];
  const float* g_w2  = (const float*)d_in[9];
  const float* g_b2  = (const float*)d_in[10];
  const float* in_w  = (const float*)d_in[11];
  const float* in_b  = (const float*)d_in[12];
  const float* out_w = (const float*)d_in[13];
  const float* out_b = (const float*)d_in[14];
  const float* ln_w  = (const float*)d_in[15];
  const float* ln_b  = (const float*)d_in[16];
  unsigned char* ws = (unsigned char*)d_ws;
  float* tab  = (float*)(ws + OFFB_TAB);
  float* gsum = (float*)(ws + OFFB_GSUM);
  float* glo  = (float*)(ws + OFFB_GLO);
  float* xm   = (float*)(ws + OFFB_XM);
  float* low  = (float*)(ws + OFFB_LOW);
  unsigned short* wq   = (unsigned short*)(ws + OFFB_WQ);
  unsigned short* wk   = (unsigned short*)(ws + OFFB_WK);
  unsigned short* wv   = (unsigned short*)(ws + OFFB_WV);
  unsigned short* kp2  = (unsigned short*)(ws + OFFB_KP);
  unsigned short* vtp  = (unsigned short*)(ws + OFFB_VT);
  unsigned short* wop2 = (unsigned short*)(ws + OFFB_WOP);
  unsigned short* wg1  = (unsigned short*)(ws + OFFB_WG1);
  unsigned short* wg2  = (unsigned short*)(ws + OFFB_WG2);

  hipMemsetAsync(gsum, 0, 96 * sizeof(float), stream);
  hipMemsetAsync(ws + MEMSET_OFF, 0, MEMSET_LEN, stream);
  k_pos<<<(324 * 96 + 255) / 256, 256, 0, stream>>>(pos_w, tab);
  k_wprep<<<36, 256, 0, stream>>>(in_w, out_w, l_w1, l_w2, wq, wk, wv, wop2, wg1, wg2);
  k_wav<<<576, 256, 0, stream>>>(mem, xm, low, gsum);
  k_glo<<<1, 128, 0, stream>>>(gsum, g_w1, g_b1, g_w2, g_b2, glo);
  k_gkv<<<256, 256, 0, stream>>>(xm, low, tab, wg1, wg2, l_b1, l_b2, glo,
                                 wk, wv, in_b, kp2, vtp);
  k_att4<<<dim3(256, 4), 256, 0, stream>>>(query, tab, kp2, vtp, wq, wop2, in_b, out_b,
                                           ln_w, ln_b, (float*)d_out);
}

// Round 18
// 389.760 us; speedup vs baseline: 1.0865x; 1.0865x over previous
//
#include <hip/hip_runtime.h>
#include <math.h>

// Geometry: C=96, NHEAD=8, dh=12 (pad 16), D,H,W=24,96,96; wavelet grid 12,48,48
// windows 4x8x8=256, Lq=864 (54 m-tiles of 16), Lk=108 (pad 112/128)
// pi-permutation on k (and pi' on d) makes PV/out-proj B-fragments lane-local:
//   pi(k):  p = (nt>>1)*32 + gk*8 + (nt&1)*4 + r   where k = 16nt + 4gk + r
//   pi'(h,d): p = (h>>1)*32 + (d>>2)*8 + (h&1)*4 + (d&3)
// FROZEN at r12 (best verified: 390.1 us, absmax 0.03125). Rejected on k_att4:
//   >2 waves/SIMD (NaN r11/r14), LDS staging (r7-9), setprio (r15), head pairing
//   (spill regression r17), K/V locality regrouping (neutral r13).

using short8 = __attribute__((ext_vector_type(8))) short;
using f32x4  = __attribute__((ext_vector_type(4))) float;

__device__ __forceinline__ unsigned short f2bf(float f) {
  unsigned u = __builtin_bit_cast(unsigned, f);
  unsigned r = u + 0x7fffu + ((u >> 16) & 1u);
  return (unsigned short)(r >> 16);
}
__device__ __forceinline__ unsigned cvtpk(float a, float b) {
  unsigned r;
  asm("v_cvt_pk_bf16_f32 %0, %1, %2" : "=v"(r) : "v"(a), "v"(b));
  return r;
}
__device__ __forceinline__ short8 mk8(unsigned a, unsigned b, unsigned c, unsigned d) {
  union { unsigned u[4]; short8 s; } x;
  x.u[0] = a; x.u[1] = b; x.u[2] = c; x.u[3] = d;
  return x.s;
}

// workspace byte offsets (high-water ~37.2 MB; round-1 proved >=53.2 MB usable)
#define OFFB_TAB   0u          // 31104 f32
#define OFFB_GSUM  124416u
#define OFFB_GLO   124800u
#define OFFB_XM    125184u     // 2654208 f32 (reused in-place as fre)
#define OFFB_LOW   10742016u   // 2654208 f32
#define OFFB_WQ    21358848u   // 9216 bf16
#define OFFB_WK    21377280u
#define OFFB_WV    21395712u
#define OFFB_KP    21414144u   // kp2[(nw*8+h)*112+kk][16]: 7340032 B (pads zero)
#define OFFB_VT    28754176u   // vtp[(nw*8+h)*16+d][128 pi-cols]: 8388608 B (pads zero)
#define OFFB_WOP   37142784u   // wop2[96][128 pi'-cols]: 24576 B (pads zero)
#define OFFB_WG1   37167360u   // 9216 bf16 gate W1
#define OFFB_WG2   37185792u   // 9216 bf16 gate W2
#define MEMSET_OFF 21414144u
#define MEMSET_LEN 15753216u   // kp2 + vtp + wop2 (wg1/wg2 fully written by k_wprep)

// ---------------- pos tables: tab[p*96+c], p in [0,324) ----------------
__global__ void k_pos(const float* __restrict__ pos_w, float* __restrict__ tab) {
  int idx = blockIdx.x * 256 + threadIdx.x;
  if (idx >= 324 * 96) return;
  int c = idx % 96, p = idx / 96;
  int Dm, fo, pl;
  if (p < 24)       { Dm = 24; fo = 0;   pl = p; }
  else if (p < 120) { Dm = 96; fo = 64;  pl = p - 24; }
  else if (p < 216) { Dm = 96; fo = 128; pl = p - 120; }
  else if (p < 228) { Dm = 12; fo = 0;   pl = p - 216; }
  else if (p < 276) { Dm = 48; fo = 64;  pl = p - 228; }
  else              { Dm = 48; fo = 128; pl = p - 276; }
  float pos = (float)pl / ((float)(Dm - 1) + 1e-6f) * 6.2831853071795864769f;
  float acc = 0.f;
  for (int i = 0; i < 32; ++i) {
    float inv = __expf((float)i * -0.2878231366242558f);  // 10000^(-i/32)
    float a = pos * inv;
    acc += sinf(a) * pos_w[c * 192 + fo + 2 * i] + cosf(a) * pos_w[c * 192 + fo + 2 * i + 1];
  }
  tab[p * 96 + c] = acc;
}

// ---------------- weight prep: f32 -> bf16 (wop2 pi'-permuted; gate W1/W2 added) ----------------
__global__ void k_wprep(const float* __restrict__ in_w, const float* __restrict__ out_w,
                        const float* __restrict__ l_w1, const float* __restrict__ l_w2,
                        unsigned short* __restrict__ wq, unsigned short* __restrict__ wk,
                        unsigned short* __restrict__ wv, unsigned short* __restrict__ wop2,
                        unsigned short* __restrict__ wg1, unsigned short* __restrict__ wg2) {
  int i = blockIdx.x * 256 + threadIdx.x;
  if (i < 9216) {
    wq[i] = f2bf(in_w[i]);
    wk[i] = f2bf(in_w[9216 + i]);
    wv[i] = f2bf(in_w[18432 + i]);
    wg1[i] = f2bf(l_w1[i]);
    wg2[i] = f2bf(l_w2[i]);
    int co = i / 96, ci = i % 96;
    int hh = ci / 12, dd = ci % 12;
    wop2[co * 128 + (hh >> 1) * 32 + (dd >> 2) * 8 + (hh & 1) * 4 + (dd & 3)] = f2bf(out_w[i]);
  }
}

// ---------------- wavelet: low = s3*sum8, xm = 2sqrt2*x(odd,odd,odd) ----------------
__global__ void k_wav(const float* __restrict__ mem, float* __restrict__ xm_g,
                      float* __restrict__ low_g, float* __restrict__ gsum) {
  __shared__ float sxm[96][49];
  __shared__ float slow[96][49];
  int dk = blockIdx.x / 48, hk = blockIdx.x % 48;
  int tid = threadIdx.x;
  for (int idx = tid; idx < 96 * 48; idx += 256) {
    int wk = idx % 48, c = idx / 48;
    const float* p = mem + (((size_t)c * 24 + 2 * dk) * 96 + 2 * hk) * 96 + 2 * wk;
    float s = p[0] + p[1] + p[96] + p[97];
    const float* p2 = p + 96 * 96;
    float x111 = p2[97];
    s += p2[0] + p2[1] + p2[96] + x111;
    sxm[c][wk] = 2.8284271247461903f * x111;
    slow[c][wk] = 0.35355339059327373f * s;
  }
  __syncthreads();
  int n0 = (dk * 48 + hk) * 48;
  for (int idx = tid; idx < 96 * 48; idx += 256) {
    int c = idx % 96, t = idx / 96;
    xm_g[(size_t)(n0 + t) * 96 + c] = sxm[c][t];
    low_g[(size_t)(n0 + t) * 96 + c] = slow[c][t];
  }
  if (tid < 96) {
    float a = 0.f;
    for (int t = 0; t < 48; ++t) a += sxm[tid][t];
    atomicAdd(&gsum[tid], a);
  }
}

// ---------------- global gate MLP (1 block) ----------------
__global__ void k_glo(const float* __restrict__ gsum, const float* __restrict__ g_w1,
                      const float* __restrict__ g_b1, const float* __restrict__ g_w2,
                      const float* __restrict__ g_b2, float* __restrict__ glo) {
  __shared__ float sg[96], sh[96];
  int t = threadIdx.x;
  if (t < 96) sg[t] = gsum[t] * (1.f / 27648.f);
  __syncthreads();
  if (t < 96) {
    float a = g_b1[t];
    for (int i = 0; i < 96; ++i) a += sg[i] * g_w1[t * 96 + i];
    sh[t] = fmaxf(a, 0.f);
  }
  __syncthreads();
  if (t < 96) {
    float a = g_b2[t];
    for (int i = 0; i < 96; ++i) a += sh[i] * g_w2[t * 96 + i];
    glo[t] = a;
  }
}

// ---------------- local gating MLP + fre via MFMA (in-place xm->fre) ----------------
__global__ __launch_bounds__(256) void k_gate2(
    const float* xm_g, const float* __restrict__ low_g,
    const unsigned short* __restrict__ wg1, const unsigned short* __restrict__ wg2,
    const float* __restrict__ l_b1, const float* __restrict__ l_b2,
    const float* __restrict__ glo, float* fre) {
  __shared__ unsigned short sXin[112 * 104];
  __shared__ unsigned short sH[112 * 104];
  int tid = threadIdx.x;
  int n0 = blockIdx.x * 108;   // 256 blocks * 108 tokens = 27648
  for (int idx = tid; idx < 112 * 48; idx += 256) {
    int row = idx % 112, cop = idx / 112;
    int co = cop * 2;
    unsigned pk = 0;
    if (row < 108) {
      float f0 = xm_g[(size_t)(n0 + row) * 96 + co];
      float f1 = xm_g[(size_t)(n0 + row) * 96 + co + 1];
      pk = (unsigned)f2bf(f0) | ((unsigned)f2bf(f1) << 16);
    }
    *(unsigned*)(&sXin[row * 104 + co]) = pk;
  }
  __syncthreads();
  int wave = tid >> 6, lane = tid & 63, l15 = lane & 15, g = lane >> 4;
  for (int mtk = wave; mtk < 7; mtk += 4) {
    f32x4 D[6];
    #pragma unroll
    for (int nt = 0; nt < 6; ++nt) D[nt] = f32x4{0.f, 0.f, 0.f, 0.f};
    #pragma unroll
    for (int ks = 0; ks < 3; ++ks) {
      short8 a = *(const short8*)(&sXin[(mtk * 16 + l15) * 104 + ks * 32 + g * 8]);
      #pragma unroll
      for (int nt = 0; nt < 6; ++nt) {
        short8 b = *(const short8*)(&wg1[(nt * 16 + l15) * 96 + ks * 32 + g * 8]);
        D[nt] = __builtin_amdgcn_mfma_f32_16x16x32_bf16(a, b, D[nt], 0, 0, 0);
      }
    }
    #pragma unroll
    for (int nt = 0; nt < 6; ++nt) {
      int co = nt * 16 + l15;
      float b1v = l_b1[co];
      #pragma unroll
      for (int r = 0; r < 4; ++r) {
        float h = fmaxf(D[nt][r] + b1v, 0.f);
        float h2 = __shfl_xor(h, 1);
        if (!(l15 & 1)) {
          int row = mtk * 16 + g * 4 + r;
          *(unsigned*)(&sH[row * 104 + co]) = (unsigned)f2bf(h) | ((unsigned)f2bf(h2) << 16);
        }
      }
    }
    asm volatile("s_waitcnt lgkmcnt(0)" ::: "memory");
    f32x4 A[6];
    #pragma unroll
    for (int nt = 0; nt < 6; ++nt) A[nt] = f32x4{0.f, 0.f, 0.f, 0.f};
    #pragma unroll
    for (int ks = 0; ks < 3; ++ks) {
      short8 a = *(const short8*)(&sH[(mtk * 16 + l15) * 104 + ks * 32 + g * 8]);
      #pragma unroll
      for (int nt = 0; nt < 6; ++nt) {
        short8 b = *(const short8*)(&wg2[(nt * 16 + l15) * 96 + ks * 32 + g * 8]);
        A[nt] = __builtin_amdgcn_mfma_f32_16x16x32_bf16(a, b, A[nt], 0, 0, 0);
      }
    }
    #pragma unroll
    for (int nt = 0; nt < 6; ++nt) {
      int co = nt * 16 + l15;
      float gb = l_b2[co] + glo[co];
      #pragma unroll
      for (int r = 0; r < 4; ++r) {
        int row = mtk * 16 + g * 4 + r;
        if (row < 108) {
          size_t off = (size_t)(n0 + row) * 96 + co;
          float wgv = 1.f / (1.f + __expf(-(A[nt][r] + gb)));
          float xv = xm_g[off], lo = low_g[off];
          fre[off] = wgv * (xv - lo) + lo;
        }
      }
    }
  }
}

// ---------------- k/v projection (MFMA) -> kp2[(nw8+h)*112+kk][16], vtp[(nw8+h)*16+d][128 pi] ----
__global__ __launch_bounds__(256) void k_kv2(
    const float* __restrict__ fre, const float* __restrict__ tab,
    const unsigned short* __restrict__ wk, const unsigned short* __restrict__ wv,
    const float* __restrict__ in_b,
    unsigned short* __restrict__ kp2, unsigned short* __restrict__ vtp) {
  __shared__ unsigned short sKin[112 * 104];
  __shared__ unsigned short sVin[112 * 104];
  __shared__ unsigned short sVt[4 * 96 * 18];
  int tid = threadIdx.x, nw = blockIdx.x;
  int dg = nw >> 6, hg = (nw >> 3) & 7, wg = nw & 7;
  for (int idx = tid; idx < 108 * 48; idx += 256) {
    int row = idx % 108, cop = idx / 108;
    int ld = row / 36, lh = (row / 6) % 6, lw = row % 6;
    int dk = dg * 3 + ld, hk = hg * 6 + lh, wk_ = wg * 6 + lw;
    int n = (dk * 48 + hk) * 48 + wk_;
    int co = cop * 2;
    float f0 = fre[(size_t)n * 96 + co], f1 = fre[(size_t)n * 96 + co + 1];
    float p0 = tab[20736 + dk * 96 + co] + tab[21888 + hk * 96 + co] + tab[26496 + wk_ * 96 + co];
    float p1 = tab[20736 + dk * 96 + co + 1] + tab[21888 + hk * 96 + co + 1] + tab[26496 + wk_ * 96 + co + 1];
    *(unsigned*)(&sKin[row * 104 + co]) = (unsigned)f2bf(f0 + p0) | ((unsigned)f2bf(f1 + p1) << 16);
    *(unsigned*)(&sVin[row * 104 + co]) = (unsigned)f2bf(f0) | ((unsigned)f2bf(f1) << 16);
  }
  __syncthreads();
  int wave = tid >> 6, lane = tid & 63, l15 = lane & 15, g = lane >> 4;
  for (int mtk = wave; mtk < 7; mtk += 4) {
    f32x4 DK[6], DV[6];
    #pragma unroll
    for (int nt = 0; nt < 6; ++nt) { DK[nt] = f32x4{0.f,0.f,0.f,0.f}; DV[nt] = f32x4{0.f,0.f,0.f,0.f}; }
    #pragma unroll
    for (int ks = 0; ks < 3; ++ks) {
      short8 ak = *(const short8*)(&sKin[(mtk * 16 + l15) * 104 + ks * 32 + g * 8]);
      short8 av = *(const short8*)(&sVin[(mtk * 16 + l15) * 104 + ks * 32 + g * 8]);
      #pragma unroll
      for (int nt = 0; nt < 6; ++nt) {
        short8 bk = *(const short8*)(&wk[(nt * 16 + l15) * 96 + ks * 32 + g * 8]);
        short8 bv = *(const short8*)(&wv[(nt * 16 + l15) * 96 + ks * 32 + g * 8]);
        DK[nt] = __builtin_amdgcn_mfma_f32_16x16x32_bf16(ak, bk, DK[nt], 0, 0, 0);
        DV[nt] = __builtin_amdgcn_mfma_f32_16x16x32_bf16(av, bv, DV[nt], 0, 0, 0);
      }
    }
    #pragma unroll
    for (int nt = 0; nt < 6; ++nt) {
      int co = nt * 16 + l15;
      float bk_ = in_b[96 + co], bv_ = in_b[192 + co];
      #pragma unroll
      for (int r = 0; r < 4; ++r) {
        int row = g * 4 + r;
        int kk = mtk * 16 + row;
        float vk = DK[nt][r] + bk_;
        float vk2 = __shfl_xor(vk, 1);
        if (!(l15 & 1) && kk < 108) {
          unsigned pk = (unsigned)f2bf(vk) | ((unsigned)f2bf(vk2) << 16);
          *(unsigned*)(&kp2[((size_t)(nw * 8 + co / 12) * 112 + kk) * 16 + co % 12]) = pk;
        }
        float vv = DV[nt][r] + bv_;
        sVt[wave * 1728 + co * 18 + row] = f2bf(vv);
      }
    }
    asm volatile("s_waitcnt lgkmcnt(0)" ::: "memory");
    int cnt = (mtk == 6) ? 12 : 16;
    for (int co = lane; co < 96; co += 64) {
      int hh = co / 12, dd = co % 12;
      size_t vrowb = ((size_t)(nw * 8 + hh) * 16 + dd) * 128;
      for (int kk2 = 0; kk2 < cnt; kk2 += 2) {
        unsigned v = *(const unsigned*)(&sVt[wave * 1728 + co * 18 + kk2]);
        int p = (mtk >> 1) * 32 + (kk2 >> 2) * 8 + (mtk & 1) * 4 + (kk2 & 3);
        *(unsigned*)(&vtp[vrowb + p]) = v;
      }
    }
  }
}

// ---------------- per-head: swapped QK^T + lane-local softmax + register PV ----------------
__device__ __forceinline__ f32x4 proc_head(
    const unsigned short* qtile, const unsigned short* kb, const unsigned short* vb,
    int h, int lane, int l15, int g) {
  short8 bq = short8{0,0,0,0,0,0,0,0};
  if (lane < 32) bq = *(const short8*)(&qtile[l15 * 136 + h * 16 + g * 8]);
  short8 ak[7];
  #pragma unroll
  for (int nt = 0; nt < 7; ++nt) {
    ak[nt] = short8{0,0,0,0,0,0,0,0};
    if (lane < 32) ak[nt] = *(const short8*)(&kb[((size_t)h * 112 + nt * 16 + l15) * 16 + g * 8]);
  }
  f32x4 S[7];
  #pragma unroll
  for (int nt = 0; nt < 7; ++nt)
    S[nt] = __builtin_amdgcn_mfma_f32_16x16x32_bf16(ak[nt], bq, f32x4{0.f,0.f,0.f,0.f}, 0, 0, 0);
  float mx = -3e38f;
  #pragma unroll
  for (int nt = 0; nt < 6; ++nt) {
    #pragma unroll
    for (int r = 0; r < 4; ++r) mx = fmaxf(mx, S[nt][r]);
  }
  if (g < 3) {
    #pragma unroll
    for (int r = 0; r < 4; ++r) mx = fmaxf(mx, S[6][r]);
  }
  mx = fmaxf(mx, __shfl_xor(mx, 16));
  mx = fmaxf(mx, __shfl_xor(mx, 32));
  float sum = 0.f;
  #pragma unroll
  for (int nt = 0; nt < 7; ++nt) {
    #pragma unroll
    for (int r = 0; r < 4; ++r) {
      float e = __expf(S[nt][r] - mx);
      if (nt == 6 && g == 3) e = 0.f;
      S[nt][r] = e;
      sum += e;
    }
  }
  sum += __shfl_xor(sum, 16);
  sum += __shfl_xor(sum, 32);
  float inv = 1.f / sum;
  short8 av[4];
  #pragma unroll
  for (int ks = 0; ks < 4; ++ks)
    av[ks] = *(const short8*)(&vb[((size_t)h * 16 + l15) * 128 + ks * 32 + g * 8]);
  f32x4 o = f32x4{0.f, 0.f, 0.f, 0.f};
  #pragma unroll
  for (int ks = 0; ks < 4; ++ks) {
    unsigned w0 = cvtpk(S[2 * ks][0], S[2 * ks][1]);
    unsigned w1 = cvtpk(S[2 * ks][2], S[2 * ks][3]);
    unsigned w2 = 0, w3 = 0;
    if (ks < 3) {
      w2 = cvtpk(S[2 * ks + 1][0], S[2 * ks + 1][1]);
      w3 = cvtpk(S[2 * ks + 1][2], S[2 * ks + 1][3]);
    }
    short8 pa = mk8(w0, w1, w2, w3);
    o = __builtin_amdgcn_mfma_f32_16x16x32_bf16(av[ks], pa, o, 0, 0, 0);
  }
  o[0] *= inv; o[1] *= inv; o[2] *= inv; o[3] *= inv;
  return o;
}

// ---------------- fused attention v4b (EXACT r12): register softmax/PV, batched loads ----------------
__global__ __launch_bounds__(256, 2) void k_att4(
    const float* __restrict__ query, const float* __restrict__ tab,
    const unsigned short* __restrict__ kp2, const unsigned short* __restrict__ vtp,
    const unsigned short* __restrict__ wq, const unsigned short* __restrict__ wop2,
    const float* __restrict__ in_b, const float* __restrict__ out_b,
    const float* __restrict__ ln_w, const float* __restrict__ ln_b,
    float* __restrict__ out) {
  __shared__ __align__(16) unsigned char smem[34816];
  int tid = threadIdx.x;
  int nw = blockIdx.x, part = blockIdx.y;
  int dg = nw >> 6, hg = (nw >> 3) & 7, wg = nw & 7;
  int wave = tid >> 6, lane = tid & 63, l15 = lane & 15, g = lane >> 4;
  unsigned char* wbase = smem + wave * 8704;
  unsigned short* qtile = (unsigned short*)wbase;   // [16][136] head-padded scaled Q
  unsigned short* sPq   = qtile + 2176;             // [16][136] qin staging
  int wid = part * 4 + wave;                        // [0,16)

  for (int c = lane; c < 544; c += 64)
    *(int4*)(wbase + c * 16) = int4{0, 0, 0, 0};
  asm volatile("s_waitcnt lgkmcnt(0)" ::: "memory");

  const float scale = 0.28867513459481287f;  // 1/sqrt(12), folded into q
  float biasq[6];
  #pragma unroll
  for (int nt = 0; nt < 6; ++nt) biasq[nt] = in_b[nt * 16 + l15];
  const unsigned short* kb = kp2 + (size_t)nw * 8 * 112 * 16;
  const unsigned short* vb = vtp + (size_t)nw * 8 * 16 * 128;

  for (int mt = wid; mt < 54; mt += 16) {
    for (int c = lane; c < 16 * 48; c += 64) {
      int row = c & 15, cop = c >> 4;
      int co = cop * 2;
      int l = mt * 16 + row;
      int ld = l / 144, lh = (l / 12) % 12, lw = l % 12;
      int d = dg * 6 + ld, h = hg * 12 + lh, w = wg * 12 + lw;
      size_t qoff = (((size_t)co * 24 + d) * 96 + h) * 96 + w;
      float v0 = query[qoff] + tab[d * 96 + co] + tab[2304 + h * 96 + co] + tab[11520 + w * 96 + co];
      float v1 = query[qoff + 221184] + tab[d * 96 + co + 1] + tab[2304 + h * 96 + co + 1] + tab[11520 + w * 96 + co + 1];
      *(unsigned*)(&sPq[row * 136 + co]) = (unsigned)f2bf(v0) | ((unsigned)f2bf(v1) << 16);
    }
    asm volatile("s_waitcnt lgkmcnt(0)" ::: "memory");
    {
      f32x4 QD[6];
      #pragma unroll
      for (int nt = 0; nt < 6; ++nt) QD[nt] = f32x4{0.f, 0.f, 0.f, 0.f};
      #pragma unroll
      for (int ks = 0; ks < 3; ++ks) {
        short8 a = *(const short8*)(&sPq[l15 * 136 + ks * 32 + g * 8]);
        #pragma unroll
        for (int nt = 0; nt < 6; ++nt) {
          short8 bw = *(const short8*)(&wq[(nt * 16 + l15) * 96 + ks * 32 + g * 8]);
          QD[nt] = __builtin_amdgcn_mfma_f32_16x16x32_bf16(a, bw, QD[nt], 0, 0, 0);
        }
      }
      #pragma unroll
      for (int nt = 0; nt < 6; ++nt) {
        int co = nt * 16 + l15;
        #pragma unroll
        for (int r = 0; r < 4; ++r) {
          float v = (QD[nt][r] + biasq[nt]) * scale;
          float v2 = __shfl_xor(v, 1);
          if (!(l15 & 1)) {
            int row = g * 4 + r;
            unsigned pk = (unsigned)f2bf(v) | ((unsigned)f2bf(v2) << 16);
            *(unsigned*)(&qtile[row * 136 + (co / 12) * 16 + co % 12]) = pk;
          }
        }
      }
    }
    asm volatile("s_waitcnt lgkmcnt(0)" ::: "memory");
    f32x4 R[6];
    #pragma unroll
    for (int nt = 0; nt < 6; ++nt) R[nt] = f32x4{0.f, 0.f, 0.f, 0.f};
    #pragma unroll
    for (int hp = 0; hp < 4; ++hp) {
      f32x4 oA = proc_head(qtile, kb, vb, 2 * hp, lane, l15, g);
      f32x4 oB = proc_head(qtile, kb, vb, 2 * hp + 1, lane, l15, g);
      short8 pb = mk8(cvtpk(oA[0], oA[1]), cvtpk(oA[2], oA[3]),
                      cvtpk(oB[0], oB[1]), cvtpk(oB[2], oB[3]));
      #pragma unroll
      for (int nt = 0; nt < 6; ++nt) {
        short8 aw = *(const short8*)(&wop2[(nt * 16 + l15) * 128 + hp * 32 + g * 8]);
        R[nt] = __builtin_amdgcn_mfma_f32_16x16x32_bf16(aw, pb, R[nt], 0, 0, 0);
      }
    }
    {
      int l = mt * 16 + l15;
      int ld = l / 144, lh = (l / 12) % 12, lw = l % 12;
      int d = dg * 6 + ld, h_ = hg * 12 + lh, w_ = wg * 12 + lw;
      size_t sp = ((size_t)d * 96 + h_) * 96 + w_;
      float s = 0.f, s2 = 0.f;
      #pragma unroll
      for (int nt = 0; nt < 6; ++nt) {
        #pragma unroll
        for (int r = 0; r < 4; ++r) {
          int co = nt * 16 + 4 * g + r;
          float v = R[nt][r] + out_b[co] + query[(size_t)co * 221184 + sp];
          R[nt][r] = v;
          s += v; s2 += v * v;
        }
      }
      s += __shfl_xor(s, 16); s2 += __shfl_xor(s2, 16);
      s += __shfl_xor(s, 32); s2 += __shfl_xor(s2, 32);
      float mu = s * (1.f / 96.f);
      float var = s2 * (1.f / 96.f) - mu * mu;
      float rstd = rsqrtf(var + 1e-5f);
      #pragma unroll
      for (int nt = 0; nt < 6; ++nt) {
        #pragma unroll
        for (int r = 0; r < 4; ++r) {
          int co = nt * 16 + 4 * g + r;
          out[(size_t)co * 221184 + sp] = (R[nt][r] - mu) * rstd * ln_w[co] + ln_b[co];
        }
      }
    }
  } // m-tiles
}

extern "C" void kernel_launch(void* const* d_in, const int* in_sizes, int n_in,
                              void* d_out, int out_size, void* d_ws, size_t ws_size,
                              hipStream_t stream) {
  const float* query = (const float*)d_in[0];
  const float* mem   = (const float*)d_in[1];
  const float* pos_w = (const float*)d_in[2];
  const float* l_w1  = (const float*)d_in[3];
  const float* l_b1  = (const float*)d_in[4];
  const float* l_w2  = (const float*)d_in[5];
  const float* l_b2  = (const float*)d_in[6];
  const float* g_w1  = (const float*)d_in[7];
  const float* g_b1  = (const float*)d_in[8];
  const float* g_w2  = (const float*)d_in[9];
  const float* g_b2  = (const float*)d_in[10];
  const float* in_w  = (const float*)d_in[11];
  const float* in_b  = (const float*)d_in[12];
  const float* out_w = (const float*)d_in[13];
  const float* out_b = (const float*)d_in[14];
  const float* ln_w  = (const float*)d_in[15];
  const float* ln_b  = (const float*)d_in[16];
  unsigned char* ws = (unsigned char*)d_ws;
  float* tab  = (float*)(ws + OFFB_TAB);
  float* gsum = (float*)(ws + OFFB_GSUM);
  float* glo  = (float*)(ws + OFFB_GLO);
  float* xm   = (float*)(ws + OFFB_XM);   // reused in-place as fre
  float* low  = (float*)(ws + OFFB_LOW);
  unsigned short* wq   = (unsigned short*)(ws + OFFB_WQ);
  unsigned short* wk   = (unsigned short*)(ws + OFFB_WK);
  unsigned short* wv   = (unsigned short*)(ws + OFFB_WV);
  unsigned short* kp2  = (unsigned short*)(ws + OFFB_KP);
  unsigned short* vtp  = (unsigned short*)(ws + OFFB_VT);
  unsigned short* wop2 = (unsigned short*)(ws + OFFB_WOP);
  unsigned short* wg1  = (unsigned short*)(ws + OFFB_WG1);
  unsigned short* wg2  = (unsigned short*)(ws + OFFB_WG2);

  hipMemsetAsync(gsum, 0, 96 * sizeof(float), stream);
  hipMemsetAsync(ws + MEMSET_OFF, 0, MEMSET_LEN, stream);
  k_pos<<<(324 * 96 + 255) / 256, 256, 0, stream>>>(pos_w, tab);
  k_wprep<<<36, 256, 0, stream>>>(in_w, out_w, l_w1, l_w2, wq, wk, wv, wop2, wg1, wg2);
  k_wav<<<576, 256, 0, stream>>>(mem, xm, low, gsum);
  k_glo<<<1, 128, 0, stream>>>(gsum, g_w1, g_b1, g_w2, g_b2, glo);
  k_gate2<<<256, 256, 0, stream>>>(xm, low, wg1, wg2, l_b1, l_b2, glo, xm);
  k_kv2<<<256, 256, 0, stream>>>(xm, tab, wk, wv, in_b, kp2, vtp);
  k_att4<<<dim3(256, 4), 256, 0, stream>>>(query, tab, kp2, vtp, wq, wop2, in_b, out_b,
                                           ln_w, ln_b, (float*)d_out);
}

// Round 19
// 386.544 us; speedup vs baseline: 1.0955x; 1.0083x over previous
//
#include <hip/hip_runtime.h>
#include <math.h>

// Geometry: C=96, NHEAD=8, dh=12 (pad 16), D,H,W=24,96,96; wavelet grid 12,48,48
// windows 4x8x8=256, Lq=864 (54 m-tiles of 16), Lk=108 (pad 112/128)
// pi-permutation on k (and pi' on d) makes PV/out-proj B-fragments lane-local:
//   pi(k):  p = (nt>>1)*32 + gk*8 + (nt&1)*4 + r   where k = 16nt + 4gk + r
//   pi'(h,d): p = (h>>1)*32 + (d>>2)*8 + (h&1)*4 + (d&3)
// FROZEN at r12 (best verified: ~390 us, absmax 0.03125). Rejected on k_att4:
//   >2 waves/SIMD (NaN r11/r14), LDS staging (r7-9), setprio (r15), head pairing
//   (spill regression r17), K/V locality regrouping (neutral r13).
// r19 delta: k_pos + k_wprep fused into one dispatch (independent outputs).

using short8 = __attribute__((ext_vector_type(8))) short;
using f32x4  = __attribute__((ext_vector_type(4))) float;

__device__ __forceinline__ unsigned short f2bf(float f) {
  unsigned u = __builtin_bit_cast(unsigned, f);
  unsigned r = u + 0x7fffu + ((u >> 16) & 1u);
  return (unsigned short)(r >> 16);
}
__device__ __forceinline__ unsigned cvtpk(float a, float b) {
  unsigned r;
  asm("v_cvt_pk_bf16_f32 %0, %1, %2" : "=v"(r) : "v"(a), "v"(b));
  return r;
}
__device__ __forceinline__ short8 mk8(unsigned a, unsigned b, unsigned c, unsigned d) {
  union { unsigned u[4]; short8 s; } x;
  x.u[0] = a; x.u[1] = b; x.u[2] = c; x.u[3] = d;
  return x.s;
}

// workspace byte offsets (high-water ~37.2 MB; round-1 proved >=53.2 MB usable)
#define OFFB_TAB   0u          // 31104 f32
#define OFFB_GSUM  124416u
#define OFFB_GLO   124800u
#define OFFB_XM    125184u     // 2654208 f32 (reused in-place as fre)
#define OFFB_LOW   10742016u   // 2654208 f32
#define OFFB_WQ    21358848u   // 9216 bf16
#define OFFB_WK    21377280u
#define OFFB_WV    21395712u
#define OFFB_KP    21414144u   // kp2[(nw*8+h)*112+kk][16]: 7340032 B (pads zero)
#define OFFB_VT    28754176u   // vtp[(nw*8+h)*16+d][128 pi-cols]: 8388608 B (pads zero)
#define OFFB_WOP   37142784u   // wop2[96][128 pi'-cols]: 24576 B (pads zero)
#define OFFB_WG1   37167360u   // 9216 bf16 gate W1
#define OFFB_WG2   37185792u   // 9216 bf16 gate W2
#define MEMSET_OFF 21414144u
#define MEMSET_LEN 15753216u   // kp2 + vtp + wop2 (wg1/wg2 fully written by k_prep)

// ---------------- fused prologue prep: pos tables (blocks 0..121) + weight bf16 (122..157) ----
__global__ void k_prep(const float* __restrict__ pos_w, float* __restrict__ tab,
                       const float* __restrict__ in_w, const float* __restrict__ out_w,
                       const float* __restrict__ l_w1, const float* __restrict__ l_w2,
                       unsigned short* __restrict__ wq, unsigned short* __restrict__ wk,
                       unsigned short* __restrict__ wv, unsigned short* __restrict__ wop2,
                       unsigned short* __restrict__ wg1, unsigned short* __restrict__ wg2) {
  int b = blockIdx.x;
  if (b < 122) {
    int idx = b * 256 + threadIdx.x;
    if (idx >= 324 * 96) return;
    int c = idx % 96, p = idx / 96;
    int Dm, fo, pl;
    if (p < 24)       { Dm = 24; fo = 0;   pl = p; }
    else if (p < 120) { Dm = 96; fo = 64;  pl = p - 24; }
    else if (p < 216) { Dm = 96; fo = 128; pl = p - 120; }
    else if (p < 228) { Dm = 12; fo = 0;   pl = p - 216; }
    else if (p < 276) { Dm = 48; fo = 64;  pl = p - 228; }
    else              { Dm = 48; fo = 128; pl = p - 276; }
    float pos = (float)pl / ((float)(Dm - 1) + 1e-6f) * 6.2831853071795864769f;
    float acc = 0.f;
    for (int i = 0; i < 32; ++i) {
      float inv = __expf((float)i * -0.2878231366242558f);  // 10000^(-i/32)
      float a = pos * inv;
      acc += sinf(a) * pos_w[c * 192 + fo + 2 * i] + cosf(a) * pos_w[c * 192 + fo + 2 * i + 1];
    }
    tab[p * 96 + c] = acc;
  } else {
    int i = (b - 122) * 256 + threadIdx.x;
    if (i < 9216) {
      wq[i] = f2bf(in_w[i]);
      wk[i] = f2bf(in_w[9216 + i]);
      wv[i] = f2bf(in_w[18432 + i]);
      wg1[i] = f2bf(l_w1[i]);
      wg2[i] = f2bf(l_w2[i]);
      int co = i / 96, ci = i % 96;
      int hh = ci / 12, dd = ci % 12;
      wop2[co * 128 + (hh >> 1) * 32 + (dd >> 2) * 8 + (hh & 1) * 4 + (dd & 3)] = f2bf(out_w[i]);
    }
  }
}

// ---------------- wavelet: low = s3*sum8, xm = 2sqrt2*x(odd,odd,odd) ----------------
__global__ void k_wav(const float* __restrict__ mem, float* __restrict__ xm_g,
                      float* __restrict__ low_g, float* __restrict__ gsum) {
  __shared__ float sxm[96][49];
  __shared__ float slow[96][49];
  int dk = blockIdx.x / 48, hk = blockIdx.x % 48;
  int tid = threadIdx.x;
  for (int idx = tid; idx < 96 * 48; idx += 256) {
    int wk = idx % 48, c = idx / 48;
    const float* p = mem + (((size_t)c * 24 + 2 * dk) * 96 + 2 * hk) * 96 + 2 * wk;
    float s = p[0] + p[1] + p[96] + p[97];
    const float* p2 = p + 96 * 96;
    float x111 = p2[97];
    s += p2[0] + p2[1] + p2[96] + x111;
    sxm[c][wk] = 2.8284271247461903f * x111;
    slow[c][wk] = 0.35355339059327373f * s;
  }
  __syncthreads();
  int n0 = (dk * 48 + hk) * 48;
  for (int idx = tid; idx < 96 * 48; idx += 256) {
    int c = idx % 96, t = idx / 96;
    xm_g[(size_t)(n0 + t) * 96 + c] = sxm[c][t];
    low_g[(size_t)(n0 + t) * 96 + c] = slow[c][t];
  }
  if (tid < 96) {
    float a = 0.f;
    for (int t = 0; t < 48; ++t) a += sxm[tid][t];
    atomicAdd(&gsum[tid], a);
  }
}

// ---------------- global gate MLP (1 block) ----------------
__global__ void k_glo(const float* __restrict__ gsum, const float* __restrict__ g_w1,
                      const float* __restrict__ g_b1, const float* __restrict__ g_w2,
                      const float* __restrict__ g_b2, float* __restrict__ glo) {
  __shared__ float sg[96], sh[96];
  int t = threadIdx.x;
  if (t < 96) sg[t] = gsum[t] * (1.f / 27648.f);
  __syncthreads();
  if (t < 96) {
    float a = g_b1[t];
    for (int i = 0; i < 96; ++i) a += sg[i] * g_w1[t * 96 + i];
    sh[t] = fmaxf(a, 0.f);
  }
  __syncthreads();
  if (t < 96) {
    float a = g_b2[t];
    for (int i = 0; i < 96; ++i) a += sh[i] * g_w2[t * 96 + i];
    glo[t] = a;
  }
}

// ---------------- local gating MLP + fre via MFMA (in-place xm->fre) ----------------
__global__ __launch_bounds__(256) void k_gate2(
    const float* xm_g, const float* __restrict__ low_g,
    const unsigned short* __restrict__ wg1, const unsigned short* __restrict__ wg2,
    const float* __restrict__ l_b1, const float* __restrict__ l_b2,
    const float* __restrict__ glo, float* fre) {
  __shared__ unsigned short sXin[112 * 104];
  __shared__ unsigned short sH[112 * 104];
  int tid = threadIdx.x;
  int n0 = blockIdx.x * 108;   // 256 blocks * 108 tokens = 27648
  for (int idx = tid; idx < 112 * 48; idx += 256) {
    int row = idx % 112, cop = idx / 112;
    int co = cop * 2;
    unsigned pk = 0;
    if (row < 108) {
      float f0 = xm_g[(size_t)(n0 + row) * 96 + co];
      float f1 = xm_g[(size_t)(n0 + row) * 96 + co + 1];
      pk = (unsigned)f2bf(f0) | ((unsigned)f2bf(f1) << 16);
    }
    *(unsigned*)(&sXin[row * 104 + co]) = pk;
  }
  __syncthreads();
  int wave = tid >> 6, lane = tid & 63, l15 = lane & 15, g = lane >> 4;
  for (int mtk = wave; mtk < 7; mtk += 4) {
    f32x4 D[6];
    #pragma unroll
    for (int nt = 0; nt < 6; ++nt) D[nt] = f32x4{0.f, 0.f, 0.f, 0.f};
    #pragma unroll
    for (int ks = 0; ks < 3; ++ks) {
      short8 a = *(const short8*)(&sXin[(mtk * 16 + l15) * 104 + ks * 32 + g * 8]);
      #pragma unroll
      for (int nt = 0; nt < 6; ++nt) {
        short8 b = *(const short8*)(&wg1[(nt * 16 + l15) * 96 + ks * 32 + g * 8]);
        D[nt] = __builtin_amdgcn_mfma_f32_16x16x32_bf16(a, b, D[nt], 0, 0, 0);
      }
    }
    #pragma unroll
    for (int nt = 0; nt < 6; ++nt) {
      int co = nt * 16 + l15;
      float b1v = l_b1[co];
      #pragma unroll
      for (int r = 0; r < 4; ++r) {
        float h = fmaxf(D[nt][r] + b1v, 0.f);
        float h2 = __shfl_xor(h, 1);
        if (!(l15 & 1)) {
          int row = mtk * 16 + g * 4 + r;
          *(unsigned*)(&sH[row * 104 + co]) = (unsigned)f2bf(h) | ((unsigned)f2bf(h2) << 16);
        }
      }
    }
    asm volatile("s_waitcnt lgkmcnt(0)" ::: "memory");
    f32x4 A[6];
    #pragma unroll
    for (int nt = 0; nt < 6; ++nt) A[nt] = f32x4{0.f, 0.f, 0.f, 0.f};
    #pragma unroll
    for (int ks = 0; ks < 3; ++ks) {
      short8 a = *(const short8*)(&sH[(mtk * 16 + l15) * 104 + ks * 32 + g * 8]);
      #pragma unroll
      for (int nt = 0; nt < 6; ++nt) {
        short8 b = *(const short8*)(&wg2[(nt * 16 + l15) * 96 + ks * 32 + g * 8]);
        A[nt] = __builtin_amdgcn_mfma_f32_16x16x32_bf16(a, b, A[nt], 0, 0, 0);
      }
    }
    #pragma unroll
    for (int nt = 0; nt < 6; ++nt) {
      int co = nt * 16 + l15;
      float gb = l_b2[co] + glo[co];
      #pragma unroll
      for (int r = 0; r < 4; ++r) {
        int row = mtk * 16 + g * 4 + r;
        if (row < 108) {
          size_t off = (size_t)(n0 + row) * 96 + co;
          float wgv = 1.f / (1.f + __expf(-(A[nt][r] + gb)));
          float xv = xm_g[off], lo = low_g[off];
          fre[off] = wgv * (xv - lo) + lo;
        }
      }
    }
  }
}

// ---------------- k/v projection (MFMA) -> kp2[(nw8+h)*112+kk][16], vtp[(nw8+h)*16+d][128 pi] ----
__global__ __launch_bounds__(256) void k_kv2(
    const float* __restrict__ fre, const float* __restrict__ tab,
    const unsigned short* __restrict__ wk, const unsigned short* __restrict__ wv,
    const float* __restrict__ in_b,
    unsigned short* __restrict__ kp2, unsigned short* __restrict__ vtp) {
  __shared__ unsigned short sKin[112 * 104];
  __shared__ unsigned short sVin[112 * 104];
  __shared__ unsigned short sVt[4 * 96 * 18];
  int tid = threadIdx.x, nw = blockIdx.x;
  int dg = nw >> 6, hg = (nw >> 3) & 7, wg = nw & 7;
  for (int idx = tid; idx < 108 * 48; idx += 256) {
    int row = idx % 108, cop = idx / 108;
    int ld = row / 36, lh = (row / 6) % 6, lw = row % 6;
    int dk = dg * 3 + ld, hk = hg * 6 + lh, wk_ = wg * 6 + lw;
    int n = (dk * 48 + hk) * 48 + wk_;
    int co = cop * 2;
    float f0 = fre[(size_t)n * 96 + co], f1 = fre[(size_t)n * 96 + co + 1];
    float p0 = tab[20736 + dk * 96 + co] + tab[21888 + hk * 96 + co] + tab[26496 + wk_ * 96 + co];
    float p1 = tab[20736 + dk * 96 + co + 1] + tab[21888 + hk * 96 + co + 1] + tab[26496 + wk_ * 96 + co + 1];
    *(unsigned*)(&sKin[row * 104 + co]) = (unsigned)f2bf(f0 + p0) | ((unsigned)f2bf(f1 + p1) << 16);
    *(unsigned*)(&sVin[row * 104 + co]) = (unsigned)f2bf(f0) | ((unsigned)f2bf(f1) << 16);
  }
  __syncthreads();
  int wave = tid >> 6, lane = tid & 63, l15 = lane & 15, g = lane >> 4;
  for (int mtk = wave; mtk < 7; mtk += 4) {
    f32x4 DK[6], DV[6];
    #pragma unroll
    for (int nt = 0; nt < 6; ++nt) { DK[nt] = f32x4{0.f,0.f,0.f,0.f}; DV[nt] = f32x4{0.f,0.f,0.f,0.f}; }
    #pragma unroll
    for (int ks = 0; ks < 3; ++ks) {
      short8 ak = *(const short8*)(&sKin[(mtk * 16 + l15) * 104 + ks * 32 + g * 8]);
      short8 av = *(const short8*)(&sVin[(mtk * 16 + l15) * 104 + ks * 32 + g * 8]);
      #pragma unroll
      for (int nt = 0; nt < 6; ++nt) {
        short8 bk = *(const short8*)(&wk[(nt * 16 + l15) * 96 + ks * 32 + g * 8]);
        short8 bv = *(const short8*)(&wv[(nt * 16 + l15) * 96 + ks * 32 + g * 8]);
        DK[nt] = __builtin_amdgcn_mfma_f32_16x16x32_bf16(ak, bk, DK[nt], 0, 0, 0);
        DV[nt] = __builtin_amdgcn_mfma_f32_16x16x32_bf16(av, bv, DV[nt], 0, 0, 0);
      }
    }
    #pragma unroll
    for (int nt = 0; nt < 6; ++nt) {
      int co = nt * 16 + l15;
      float bk_ = in_b[96 + co], bv_ = in_b[192 + co];
      #pragma unroll
      for (int r = 0; r < 4; ++r) {
        int row = g * 4 + r;
        int kk = mtk * 16 + row;
        float vk = DK[nt][r] + bk_;
        float vk2 = __shfl_xor(vk, 1);
        if (!(l15 & 1) && kk < 108) {
          unsigned pk = (unsigned)f2bf(vk) | ((unsigned)f2bf(vk2) << 16);
          *(unsigned*)(&kp2[((size_t)(nw * 8 + co / 12) * 112 + kk) * 16 + co % 12]) = pk;
        }
        float vv = DV[nt][r] + bv_;
        sVt[wave * 1728 + co * 18 + row] = f2bf(vv);
      }
    }
    asm volatile("s_waitcnt lgkmcnt(0)" ::: "memory");
    int cnt = (mtk == 6) ? 12 : 16;
    for (int co = lane; co < 96; co += 64) {
      int hh = co / 12, dd = co % 12;
      size_t vrowb = ((size_t)(nw * 8 + hh) * 16 + dd) * 128;
      for (int kk2 = 0; kk2 < cnt; kk2 += 2) {
        unsigned v = *(const unsigned*)(&sVt[wave * 1728 + co * 18 + kk2]);
        int p = (mtk >> 1) * 32 + (kk2 >> 2) * 8 + (mtk & 1) * 4 + (kk2 & 3);
        *(unsigned*)(&vtp[vrowb + p]) = v;
      }
    }
  }
}

// ---------------- per-head: swapped QK^T + lane-local softmax + register PV ----------------
__device__ __forceinline__ f32x4 proc_head(
    const unsigned short* qtile, const unsigned short* kb, const unsigned short* vb,
    int h, int lane, int l15, int g) {
  short8 bq = short8{0,0,0,0,0,0,0,0};
  if (lane < 32) bq = *(const short8*)(&qtile[l15 * 136 + h * 16 + g * 8]);
  short8 ak[7];
  #pragma unroll
  for (int nt = 0; nt < 7; ++nt) {
    ak[nt] = short8{0,0,0,0,0,0,0,0};
    if (lane < 32) ak[nt] = *(const short8*)(&kb[((size_t)h * 112 + nt * 16 + l15) * 16 + g * 8]);
  }
  f32x4 S[7];
  #pragma unroll
  for (int nt = 0; nt < 7; ++nt)
    S[nt] = __builtin_amdgcn_mfma_f32_16x16x32_bf16(ak[nt], bq, f32x4{0.f,0.f,0.f,0.f}, 0, 0, 0);
  float mx = -3e38f;
  #pragma unroll
  for (int nt = 0; nt < 6; ++nt) {
    #pragma unroll
    for (int r = 0; r < 4; ++r) mx = fmaxf(mx, S[nt][r]);
  }
  if (g < 3) {
    #pragma unroll
    for (int r = 0; r < 4; ++r) mx = fmaxf(mx, S[6][r]);
  }
  mx = fmaxf(mx, __shfl_xor(mx, 16));
  mx = fmaxf(mx, __shfl_xor(mx, 32));
  float sum = 0.f;
  #pragma unroll
  for (int nt = 0; nt < 7; ++nt) {
    #pragma unroll
    for (int r = 0; r < 4; ++r) {
      float e = __expf(S[nt][r] - mx);
      if (nt == 6 && g == 3) e = 0.f;
      S[nt][r] = e;
      sum += e;
    }
  }
  sum += __shfl_xor(sum, 16);
  sum += __shfl_xor(sum, 32);
  float inv = 1.f / sum;
  short8 av[4];
  #pragma unroll
  for (int ks = 0; ks < 4; ++ks)
    av[ks] = *(const short8*)(&vb[((size_t)h * 16 + l15) * 128 + ks * 32 + g * 8]);
  f32x4 o = f32x4{0.f, 0.f, 0.f, 0.f};
  #pragma unroll
  for (int ks = 0; ks < 4; ++ks) {
    unsigned w0 = cvtpk(S[2 * ks][0], S[2 * ks][1]);
    unsigned w1 = cvtpk(S[2 * ks][2], S[2 * ks][3]);
    unsigned w2 = 0, w3 = 0;
    if (ks < 3) {
      w2 = cvtpk(S[2 * ks + 1][0], S[2 * ks + 1][1]);
      w3 = cvtpk(S[2 * ks + 1][2], S[2 * ks + 1][3]);
    }
    short8 pa = mk8(w0, w1, w2, w3);
    o = __builtin_amdgcn_mfma_f32_16x16x32_bf16(av[ks], pa, o, 0, 0, 0);
  }
  o[0] *= inv; o[1] *= inv; o[2] *= inv; o[3] *= inv;
  return o;
}

// ---------------- fused attention v4b (EXACT r12): register softmax/PV, batched loads ----------------
__global__ __launch_bounds__(256, 2) void k_att4(
    const float* __restrict__ query, const float* __restrict__ tab,
    const unsigned short* __restrict__ kp2, const unsigned short* __restrict__ vtp,
    const unsigned short* __restrict__ wq, const unsigned short* __restrict__ wop2,
    const float* __restrict__ in_b, const float* __restrict__ out_b,
    const float* __restrict__ ln_w, const float* __restrict__ ln_b,
    float* __restrict__ out) {
  __shared__ __align__(16) unsigned char smem[34816];
  int tid = threadIdx.x;
  int nw = blockIdx.x, part = blockIdx.y;
  int dg = nw >> 6, hg = (nw >> 3) & 7, wg = nw & 7;
  int wave = tid >> 6, lane = tid & 63, l15 = lane & 15, g = lane >> 4;
  unsigned char* wbase = smem + wave * 8704;
  unsigned short* qtile = (unsigned short*)wbase;   // [16][136] head-padded scaled Q
  unsigned short* sPq   = qtile + 2176;             // [16][136] qin staging
  int wid = part * 4 + wave;                        // [0,16)

  for (int c = lane; c < 544; c += 64)
    *(int4*)(wbase + c * 16) = int4{0, 0, 0, 0};
  asm volatile("s_waitcnt lgkmcnt(0)" ::: "memory");

  const float scale = 0.28867513459481287f;  // 1/sqrt(12), folded into q
  float biasq[6];
  #pragma unroll
  for (int nt = 0; nt < 6; ++nt) biasq[nt] = in_b[nt * 16 + l15];
  const unsigned short* kb = kp2 + (size_t)nw * 8 * 112 * 16;
  const unsigned short* vb = vtp + (size_t)nw * 8 * 16 * 128;

  for (int mt = wid; mt < 54; mt += 16) {
    for (int c = lane; c < 16 * 48; c += 64) {
      int row = c & 15, cop = c >> 4;
      int co = cop * 2;
      int l = mt * 16 + row;
      int ld = l / 144, lh = (l / 12) % 12, lw = l % 12;
      int d = dg * 6 + ld, h = hg * 12 + lh, w = wg * 12 + lw;
      size_t qoff = (((size_t)co * 24 + d) * 96 + h) * 96 + w;
      float v0 = query[qoff] + tab[d * 96 + co] + tab[2304 + h * 96 + co] + tab[11520 + w * 96 + co];
      float v1 = query[qoff + 221184] + tab[d * 96 + co + 1] + tab[2304 + h * 96 + co + 1] + tab[11520 + w * 96 + co + 1];
      *(unsigned*)(&sPq[row * 136 + co]) = (unsigned)f2bf(v0) | ((unsigned)f2bf(v1) << 16);
    }
    asm volatile("s_waitcnt lgkmcnt(0)" ::: "memory");
    {
      f32x4 QD[6];
      #pragma unroll
      for (int nt = 0; nt < 6; ++nt) QD[nt] = f32x4{0.f, 0.f, 0.f, 0.f};
      #pragma unroll
      for (int ks = 0; ks < 3; ++ks) {
        short8 a = *(const short8*)(&sPq[l15 * 136 + ks * 32 + g * 8]);
        #pragma unroll
        for (int nt = 0; nt < 6; ++nt) {
          short8 bw = *(const short8*)(&wq[(nt * 16 + l15) * 96 + ks * 32 + g * 8]);
          QD[nt] = __builtin_amdgcn_mfma_f32_16x16x32_bf16(a, bw, QD[nt], 0, 0, 0);
        }
      }
      #pragma unroll
      for (int nt = 0; nt < 6; ++nt) {
        int co = nt * 16 + l15;
        #pragma unroll
        for (int r = 0; r < 4; ++r) {
          float v = (QD[nt][r] + biasq[nt]) * scale;
          float v2 = __shfl_xor(v, 1);
          if (!(l15 & 1)) {
            int row = g * 4 + r;
            unsigned pk = (unsigned)f2bf(v) | ((unsigned)f2bf(v2) << 16);
            *(unsigned*)(&qtile[row * 136 + (co / 12) * 16 + co % 12]) = pk;
          }
        }
      }
    }
    asm volatile("s_waitcnt lgkmcnt(0)" ::: "memory");
    f32x4 R[6];
    #pragma unroll
    for (int nt = 0; nt < 6; ++nt) R[nt] = f32x4{0.f, 0.f, 0.f, 0.f};
    #pragma unroll
    for (int hp = 0; hp < 4; ++hp) {
      f32x4 oA = proc_head(qtile, kb, vb, 2 * hp, lane, l15, g);
      f32x4 oB = proc_head(qtile, kb, vb, 2 * hp + 1, lane, l15, g);
      short8 pb = mk8(cvtpk(oA[0], oA[1]), cvtpk(oA[2], oA[3]),
                      cvtpk(oB[0], oB[1]), cvtpk(oB[2], oB[3]));
      #pragma unroll
      for (int nt = 0; nt < 6; ++nt) {
        short8 aw = *(const short8*)(&wop2[(nt * 16 + l15) * 128 + hp * 32 + g * 8]);
        R[nt] = __builtin_amdgcn_mfma_f32_16x16x32_bf16(aw, pb, R[nt], 0, 0, 0);
      }
    }
    {
      int l = mt * 16 + l15;
      int ld = l / 144, lh = (l / 12) % 12, lw = l % 12;
      int d = dg * 6 + ld, h_ = hg * 12 + lh, w_ = wg * 12 + lw;
      size_t sp = ((size_t)d * 96 + h_) * 96 + w_;
      float s = 0.f, s2 = 0.f;
      #pragma unroll
      for (int nt = 0; nt < 6; ++nt) {
        #pragma unroll
        for (int r = 0; r < 4; ++r) {
          int co = nt * 16 + 4 * g + r;
          float v = R[nt][r] + out_b[co] + query[(size_t)co * 221184 + sp];
          R[nt][r] = v;
          s += v; s2 += v * v;
        }
      }
      s += __shfl_xor(s, 16); s2 += __shfl_xor(s2, 16);
      s += __shfl_xor(s, 32); s2 += __shfl_xor(s2, 32);
      float mu = s * (1.f / 96.f);
      float var = s2 * (1.f / 96.f) - mu * mu;
      float rstd = rsqrtf(var + 1e-5f);
      #pragma unroll
      for (int nt = 0; nt < 6; ++nt) {
        #pragma unroll
        for (int r = 0; r < 4; ++r) {
          int co = nt * 16 + 4 * g + r;
          out[(size_t)co * 221184 + sp] = (R[nt][r] - mu) * rstd * ln_w[co] + ln_b[co];
        }
      }
    }
  } // m-tiles
}

extern "C" void kernel_launch(void* const* d_in, const int* in_sizes, int n_in,
                              void* d_out, int out_size, void* d_ws, size_t ws_size,
                              hipStream_t stream) {
  const float* query = (const float*)d_in[0];
  const float* mem   = (const float*)d_in[1];
  const float* pos_w = (const float*)d_in[2];
  const float* l_w1  = (const float*)d_in[3];
  const float* l_b1  = (const float*)d_in[4];
  const float* l_w2  = (const float*)d_in[5];
  const float* l_b2  = (const float*)d_in[6];
  const float* g_w1  = (const float*)d_in[7];
  const float* g_b1  = (const float*)d_in[8];
  const float* g_w2  = (const float*)d_in[9];
  const float* g_b2  = (const float*)d_in[10];
  const float* in_w  = (const float*)d_in[11];
  const float* in_b  = (const float*)d_in[12];
  const float* out_w = (const float*)d_in[13];
  const float* out_b = (const float*)d_in[14];
  const float* ln_w  = (const float*)d_in[15];
  const float* ln_b  = (const float*)d_in[16];
  unsigned char* ws = (unsigned char*)d_ws;
  float* tab  = (float*)(ws + OFFB_TAB);
  float* gsum = (float*)(ws + OFFB_GSUM);
  float* glo  = (float*)(ws + OFFB_GLO);
  float* xm   = (float*)(ws + OFFB_XM);   // reused in-place as fre
  float* low  = (float*)(ws + OFFB_LOW);
  unsigned short* wq   = (unsigned short*)(ws + OFFB_WQ);
  unsigned short* wk   = (unsigned short*)(ws + OFFB_WK);
  unsigned short* wv   = (unsigned short*)(ws + OFFB_WV);
  unsigned short* kp2  = (unsigned short*)(ws + OFFB_KP);
  unsigned short* vtp  = (unsigned short*)(ws + OFFB_VT);
  unsigned short* wop2 = (unsigned short*)(ws + OFFB_WOP);
  unsigned short* wg1  = (unsigned short*)(ws + OFFB_WG1);
  unsigned short* wg2  = (unsigned short*)(ws + OFFB_WG2);

  hipMemsetAsync(gsum, 0, 96 * sizeof(float), stream);
  hipMemsetAsync(ws + MEMSET_OFF, 0, MEMSET_LEN, stream);
  k_prep<<<158, 256, 0, stream>>>(pos_w, tab, in_w, out_w, l_w1, l_w2,
                                  wq, wk, wv, wop2, wg1, wg2);
  k_wav<<<576, 256, 0, stream>>>(mem, xm, low, gsum);
  k_glo<<<1, 128, 0, stream>>>(gsum, g_w1, g_b1, g_w2, g_b2, glo);
  k_gate2<<<256, 256, 0, stream>>>(xm, low, wg1, wg2, l_b1, l_b2, glo, xm);
  k_kv2<<<256, 256, 0, stream>>>(xm, tab, wk, wv, in_b, kp2, vtp);
  k_att4<<<dim3(256, 4), 256, 0, stream>>>(query, tab, kp2, vtp, wq, wop2, in_b, out_b,
                                           ln_w, ln_b, (float*)d_out);
}

// Round 20
// 381.007 us; speedup vs baseline: 1.1114x; 1.0145x over previous
//
#include <hip/hip_runtime.h>
#include <math.h>

// Geometry: C=96, NHEAD=8, dh=12 (pad 16), D,H,W=24,96,96; wavelet grid 12,48,48
// windows 4x8x8=256, Lq=864 (54 m-tiles of 16), Lk=108 (pad 112/128)
// pi-permutation on k (and pi' on d) makes PV/out-proj B-fragments lane-local:
//   pi(k):  p = (nt>>1)*32 + gk*8 + (nt&1)*4 + r   where k = 16nt + 4gk + r
//   pi'(h,d): p = (h>>1)*32 + (d>>2)*8 + (h&1)*4 + (d&3)
// FROZEN at r12 (best verified). Rejected on k_att4: >2 waves/SIMD (NaN r11/r14),
// LDS staging (r7-9), setprio (r15), head pairing (spill r17), locality regroup (r13).
// r19: k_pos+k_wprep fused. r20: memsets folded into k_prep (zero blocks; wop2 pads
// zeroed by weight blocks to avoid intra-kernel write race).

using short8 = __attribute__((ext_vector_type(8))) short;
using f32x4  = __attribute__((ext_vector_type(4))) float;

__device__ __forceinline__ unsigned short f2bf(float f) {
  unsigned u = __builtin_bit_cast(unsigned, f);
  unsigned r = u + 0x7fffu + ((u >> 16) & 1u);
  return (unsigned short)(r >> 16);
}
__device__ __forceinline__ unsigned cvtpk(float a, float b) {
  unsigned r;
  asm("v_cvt_pk_bf16_f32 %0, %1, %2" : "=v"(r) : "v"(a), "v"(b));
  return r;
}
__device__ __forceinline__ short8 mk8(unsigned a, unsigned b, unsigned c, unsigned d) {
  union { unsigned u[4]; short8 s; } x;
  x.u[0] = a; x.u[1] = b; x.u[2] = c; x.u[3] = d;
  return x.s;
}

// workspace byte offsets (high-water ~37.2 MB; round-1 proved >=53.2 MB usable)
#define OFFB_TAB   0u          // 31104 f32
#define OFFB_GSUM  124416u
#define OFFB_GLO   124800u
#define OFFB_XM    125184u     // 2654208 f32 (reused in-place as fre)
#define OFFB_LOW   10742016u   // 2654208 f32
#define OFFB_WQ    21358848u   // 9216 bf16
#define OFFB_WK    21377280u
#define OFFB_WV    21395712u
#define OFFB_KP    21414144u   // kp2[(nw*8+h)*112+kk][16]: 7340032 B (pads zero)
#define OFFB_VT    28754176u   // vtp[(nw*8+h)*16+d][128 pi-cols]: 8388608 B (pads zero)
#define OFFB_WOP   37142784u   // wop2[96][128 pi'-cols]: 24576 B (pads zeroed in k_prep)
#define OFFB_WG1   37167360u   // 9216 bf16 gate W1
#define OFFB_WG2   37185792u   // 9216 bf16 gate W2
#define ZERO_OFF   21414144u   // kp2 + vtp only (wop2 handled by weight blocks)
#define ZERO_INT4  983040u     // 15728640 B / 16

// ---------------- fused prologue prep: pos tables (0..121) + weights (122..157) + zero (158+) ----
__global__ void k_prep(const float* __restrict__ pos_w, float* __restrict__ tab,
                       const float* __restrict__ in_w, const float* __restrict__ out_w,
                       const float* __restrict__ l_w1, const float* __restrict__ l_w2,
                       unsigned short* __restrict__ wq, unsigned short* __restrict__ wk,
                       unsigned short* __restrict__ wv, unsigned short* __restrict__ wop2,
                       unsigned short* __restrict__ wg1, unsigned short* __restrict__ wg2,
                       float* __restrict__ gsum, unsigned char* __restrict__ zro) {
  int b = blockIdx.x;
  if (b < 122) {
    int idx = b * 256 + threadIdx.x;
    if (idx >= 324 * 96) return;
    int c = idx % 96, p = idx / 96;
    int Dm, fo, pl;
    if (p < 24)       { Dm = 24; fo = 0;   pl = p; }
    else if (p < 120) { Dm = 96; fo = 64;  pl = p - 24; }
    else if (p < 216) { Dm = 96; fo = 128; pl = p - 120; }
    else if (p < 228) { Dm = 12; fo = 0;   pl = p - 216; }
    else if (p < 276) { Dm = 48; fo = 64;  pl = p - 228; }
    else              { Dm = 48; fo = 128; pl = p - 276; }
    float pos = (float)pl / ((float)(Dm - 1) + 1e-6f) * 6.2831853071795864769f;
    float acc = 0.f;
    for (int i = 0; i < 32; ++i) {
      float inv = __expf((float)i * -0.2878231366242558f);  // 10000^(-i/32)
      float a = pos * inv;
      acc += sinf(a) * pos_w[c * 192 + fo + 2 * i] + cosf(a) * pos_w[c * 192 + fo + 2 * i + 1];
    }
    tab[p * 96 + c] = acc;
  } else if (b < 158) {
    int i = (b - 122) * 256 + threadIdx.x;
    if (i < 9216) {
      wq[i] = f2bf(in_w[i]);
      wk[i] = f2bf(in_w[9216 + i]);
      wv[i] = f2bf(in_w[18432 + i]);
      wg1[i] = f2bf(l_w1[i]);
      wg2[i] = f2bf(l_w2[i]);
      int co = i / 96, ci = i % 96;
      int hh = ci / 12, dd = ci % 12;
      wop2[co * 128 + (hh >> 1) * 32 + (dd >> 2) * 8 + (hh & 1) * 4 + (dd & 3)] = f2bf(out_w[i]);
    }
    // zero wop2 pad slots (complement of bijective pi' image): 24..31 of each 32-block
    if (i < 3072) {
      int row = i >> 5, q = i & 31;
      wop2[row * 128 + (q >> 3) * 32 + 24 + (q & 7)] = 0;
    }
  } else {
    int zb = b - 158;  // 0..1023
    if (zb == 0 && threadIdx.x < 96) gsum[threadIdx.x] = 0.f;
    for (unsigned i = (unsigned)zb * 256u + threadIdx.x; i < ZERO_INT4; i += 1024u * 256u)
      ((int4*)zro)[i] = int4{0, 0, 0, 0};
  }
}

// ---------------- wavelet: low = s3*sum8, xm = 2sqrt2*x(odd,odd,odd) ----------------
__global__ void k_wav(const float* __restrict__ mem, float* __restrict__ xm_g,
                      float* __restrict__ low_g, float* __restrict__ gsum) {
  __shared__ float sxm[96][49];
  __shared__ float slow[96][49];
  int dk = blockIdx.x / 48, hk = blockIdx.x % 48;
  int tid = threadIdx.x;
  for (int idx = tid; idx < 96 * 48; idx += 256) {
    int wk = idx % 48, c = idx / 48;
    const float* p = mem + (((size_t)c * 24 + 2 * dk) * 96 + 2 * hk) * 96 + 2 * wk;
    float s = p[0] + p[1] + p[96] + p[97];
    const float* p2 = p + 96 * 96;
    float x111 = p2[97];
    s += p2[0] + p2[1] + p2[96] + x111;
    sxm[c][wk] = 2.8284271247461903f * x111;
    slow[c][wk] = 0.35355339059327373f * s;
  }
  __syncthreads();
  int n0 = (dk * 48 + hk) * 48;
  for (int idx = tid; idx < 96 * 48; idx += 256) {
    int c = idx % 96, t = idx / 96;
    xm_g[(size_t)(n0 + t) * 96 + c] = sxm[c][t];
    low_g[(size_t)(n0 + t) * 96 + c] = slow[c][t];
  }
  if (tid < 96) {
    float a = 0.f;
    for (int t = 0; t < 48; ++t) a += sxm[tid][t];
    atomicAdd(&gsum[tid], a);
  }
}

// ---------------- global gate MLP (1 block) ----------------
__global__ void k_glo(const float* __restrict__ gsum, const float* __restrict__ g_w1,
                      const float* __restrict__ g_b1, const float* __restrict__ g_w2,
                      const float* __restrict__ g_b2, float* __restrict__ glo) {
  __shared__ float sg[96], sh[96];
  int t = threadIdx.x;
  if (t < 96) sg[t] = gsum[t] * (1.f / 27648.f);
  __syncthreads();
  if (t < 96) {
    float a = g_b1[t];
    for (int i = 0; i < 96; ++i) a += sg[i] * g_w1[t * 96 + i];
    sh[t] = fmaxf(a, 0.f);
  }
  __syncthreads();
  if (t < 96) {
    float a = g_b2[t];
    for (int i = 0; i < 96; ++i) a += sh[i] * g_w2[t * 96 + i];
    glo[t] = a;
  }
}

// ---------------- local gating MLP + fre via MFMA (in-place xm->fre) ----------------
__global__ __launch_bounds__(256) void k_gate2(
    const float* xm_g, const float* __restrict__ low_g,
    const unsigned short* __restrict__ wg1, const unsigned short* __restrict__ wg2,
    const float* __restrict__ l_b1, const float* __restrict__ l_b2,
    const float* __restrict__ glo, float* fre) {
  __shared__ unsigned short sXin[112 * 104];
  __shared__ unsigned short sH[112 * 104];
  int tid = threadIdx.x;
  int n0 = blockIdx.x * 108;   // 256 blocks * 108 tokens = 27648
  for (int idx = tid; idx < 112 * 48; idx += 256) {
    int row = idx % 112, cop = idx / 112;
    int co = cop * 2;
    unsigned pk = 0;
    if (row < 108) {
      float f0 = xm_g[(size_t)(n0 + row) * 96 + co];
      float f1 = xm_g[(size_t)(n0 + row) * 96 + co + 1];
      pk = (unsigned)f2bf(f0) | ((unsigned)f2bf(f1) << 16);
    }
    *(unsigned*)(&sXin[row * 104 + co]) = pk;
  }
  __syncthreads();
  int wave = tid >> 6, lane = tid & 63, l15 = lane & 15, g = lane >> 4;
  for (int mtk = wave; mtk < 7; mtk += 4) {
    f32x4 D[6];
    #pragma unroll
    for (int nt = 0; nt < 6; ++nt) D[nt] = f32x4{0.f, 0.f, 0.f, 0.f};
    #pragma unroll
    for (int ks = 0; ks < 3; ++ks) {
      short8 a = *(const short8*)(&sXin[(mtk * 16 + l15) * 104 + ks * 32 + g * 8]);
      #pragma unroll
      for (int nt = 0; nt < 6; ++nt) {
        short8 b = *(const short8*)(&wg1[(nt * 16 + l15) * 96 + ks * 32 + g * 8]);
        D[nt] = __builtin_amdgcn_mfma_f32_16x16x32_bf16(a, b, D[nt], 0, 0, 0);
      }
    }
    #pragma unroll
    for (int nt = 0; nt < 6; ++nt) {
      int co = nt * 16 + l15;
      float b1v = l_b1[co];
      #pragma unroll
      for (int r = 0; r < 4; ++r) {
        float h = fmaxf(D[nt][r] + b1v, 0.f);
        float h2 = __shfl_xor(h, 1);
        if (!(l15 & 1)) {
          int row = mtk * 16 + g * 4 + r;
          *(unsigned*)(&sH[row * 104 + co]) = (unsigned)f2bf(h) | ((unsigned)f2bf(h2) << 16);
        }
      }
    }
    asm volatile("s_waitcnt lgkmcnt(0)" ::: "memory");
    f32x4 A[6];
    #pragma unroll
    for (int nt = 0; nt < 6; ++nt) A[nt] = f32x4{0.f, 0.f, 0.f, 0.f};
    #pragma unroll
    for (int ks = 0; ks < 3; ++ks) {
      short8 a = *(const short8*)(&sH[(mtk * 16 + l15) * 104 + ks * 32 + g * 8]);
      #pragma unroll
      for (int nt = 0; nt < 6; ++nt) {
        short8 b = *(const short8*)(&wg2[(nt * 16 + l15) * 96 + ks * 32 + g * 8]);
        A[nt] = __builtin_amdgcn_mfma_f32_16x16x32_bf16(a, b, A[nt], 0, 0, 0);
      }
    }
    #pragma unroll
    for (int nt = 0; nt < 6; ++nt) {
      int co = nt * 16 + l15;
      float gb = l_b2[co] + glo[co];
      #pragma unroll
      for (int r = 0; r < 4; ++r) {
        int row = mtk * 16 + g * 4 + r;
        if (row < 108) {
          size_t off = (size_t)(n0 + row) * 96 + co;
          float wgv = 1.f / (1.f + __expf(-(A[nt][r] + gb)));
          float xv = xm_g[off], lo = low_g[off];
          fre[off] = wgv * (xv - lo) + lo;
        }
      }
    }
  }
}

// ---------------- k/v projection (MFMA) -> kp2[(nw8+h)*112+kk][16], vtp[(nw8+h)*16+d][128 pi] ----
__global__ __launch_bounds__(256) void k_kv2(
    const float* __restrict__ fre, const float* __restrict__ tab,
    const unsigned short* __restrict__ wk, const unsigned short* __restrict__ wv,
    const float* __restrict__ in_b,
    unsigned short* __restrict__ kp2, unsigned short* __restrict__ vtp) {
  __shared__ unsigned short sKin[112 * 104];
  __shared__ unsigned short sVin[112 * 104];
  __shared__ unsigned short sVt[4 * 96 * 18];
  int tid = threadIdx.x, nw = blockIdx.x;
  int dg = nw >> 6, hg = (nw >> 3) & 7, wg = nw & 7;
  for (int idx = tid; idx < 108 * 48; idx += 256) {
    int row = idx % 108, cop = idx / 108;
    int ld = row / 36, lh = (row / 6) % 6, lw = row % 6;
    int dk = dg * 3 + ld, hk = hg * 6 + lh, wk_ = wg * 6 + lw;
    int n = (dk * 48 + hk) * 48 + wk_;
    int co = cop * 2;
    float f0 = fre[(size_t)n * 96 + co], f1 = fre[(size_t)n * 96 + co + 1];
    float p0 = tab[20736 + dk * 96 + co] + tab[21888 + hk * 96 + co] + tab[26496 + wk_ * 96 + co];
    float p1 = tab[20736 + dk * 96 + co + 1] + tab[21888 + hk * 96 + co + 1] + tab[26496 + wk_ * 96 + co + 1];
    *(unsigned*)(&sKin[row * 104 + co]) = (unsigned)f2bf(f0 + p0) | ((unsigned)f2bf(f1 + p1) << 16);
    *(unsigned*)(&sVin[row * 104 + co]) = (unsigned)f2bf(f0) | ((unsigned)f2bf(f1) << 16);
  }
  __syncthreads();
  int wave = tid >> 6, lane = tid & 63, l15 = lane & 15, g = lane >> 4;
  for (int mtk = wave; mtk < 7; mtk += 4) {
    f32x4 DK[6], DV[6];
    #pragma unroll
    for (int nt = 0; nt < 6; ++nt) { DK[nt] = f32x4{0.f,0.f,0.f,0.f}; DV[nt] = f32x4{0.f,0.f,0.f,0.f}; }
    #pragma unroll
    for (int ks = 0; ks < 3; ++ks) {
      short8 ak = *(const short8*)(&sKin[(mtk * 16 + l15) * 104 + ks * 32 + g * 8]);
      short8 av = *(const short8*)(&sVin[(mtk * 16 + l15) * 104 + ks * 32 + g * 8]);
      #pragma unroll
      for (int nt = 0; nt < 6; ++nt) {
        short8 bk = *(const short8*)(&wk[(nt * 16 + l15) * 96 + ks * 32 + g * 8]);
        short8 bv = *(const short8*)(&wv[(nt * 16 + l15) * 96 + ks * 32 + g * 8]);
        DK[nt] = __builtin_amdgcn_mfma_f32_16x16x32_bf16(ak, bk, DK[nt], 0, 0, 0);
        DV[nt] = __builtin_amdgcn_mfma_f32_16x16x32_bf16(av, bv, DV[nt], 0, 0, 0);
      }
    }
    #pragma unroll
    for (int nt = 0; nt < 6; ++nt) {
      int co = nt * 16 + l15;
      float bk_ = in_b[96 + co], bv_ = in_b[192 + co];
      #pragma unroll
      for (int r = 0; r < 4; ++r) {
        int row = g * 4 + r;
        int kk = mtk * 16 + row;
        float vk = DK[nt][r] + bk_;
        float vk2 = __shfl_xor(vk, 1);
        if (!(l15 & 1) && kk < 108) {
          unsigned pk = (unsigned)f2bf(vk) | ((unsigned)f2bf(vk2) << 16);
          *(unsigned*)(&kp2[((size_t)(nw * 8 + co / 12) * 112 + kk) * 16 + co % 12]) = pk;
        }
        float vv = DV[nt][r] + bv_;
        sVt[wave * 1728 + co * 18 + row] = f2bf(vv);
      }
    }
    asm volatile("s_waitcnt lgkmcnt(0)" ::: "memory");
    int cnt = (mtk == 6) ? 12 : 16;
    for (int co = lane; co < 96; co += 64) {
      int hh = co / 12, dd = co % 12;
      size_t vrowb = ((size_t)(nw * 8 + hh) * 16 + dd) * 128;
      for (int kk2 = 0; kk2 < cnt; kk2 += 2) {
        unsigned v = *(const unsigned*)(&sVt[wave * 1728 + co * 18 + kk2]);
        int p = (mtk >> 1) * 32 + (kk2 >> 2) * 8 + (mtk & 1) * 4 + (kk2 & 3);
        *(unsigned*)(&vtp[vrowb + p]) = v;
      }
    }
  }
}

// ---------------- per-head: swapped QK^T + lane-local softmax + register PV ----------------
__device__ __forceinline__ f32x4 proc_head(
    const unsigned short* qtile, const unsigned short* kb, const unsigned short* vb,
    int h, int lane, int l15, int g) {
  short8 bq = short8{0,0,0,0,0,0,0,0};
  if (lane < 32) bq = *(const short8*)(&qtile[l15 * 136 + h * 16 + g * 8]);
  short8 ak[7];
  #pragma unroll
  for (int nt = 0; nt < 7; ++nt) {
    ak[nt] = short8{0,0,0,0,0,0,0,0};
    if (lane < 32) ak[nt] = *(const short8*)(&kb[((size_t)h * 112 + nt * 16 + l15) * 16 + g * 8]);
  }
  f32x4 S[7];
  #pragma unroll
  for (int nt = 0; nt < 7; ++nt)
    S[nt] = __builtin_amdgcn_mfma_f32_16x16x32_bf16(ak[nt], bq, f32x4{0.f,0.f,0.f,0.f}, 0, 0, 0);
  float mx = -3e38f;
  #pragma unroll
  for (int nt = 0; nt < 6; ++nt) {
    #pragma unroll
    for (int r = 0; r < 4; ++r) mx = fmaxf(mx, S[nt][r]);
  }
  if (g < 3) {
    #pragma unroll
    for (int r = 0; r < 4; ++r) mx = fmaxf(mx, S[6][r]);
  }
  mx = fmaxf(mx, __shfl_xor(mx, 16));
  mx = fmaxf(mx, __shfl_xor(mx, 32));
  float sum = 0.f;
  #pragma unroll
  for (int nt = 0; nt < 7; ++nt) {
    #pragma unroll
    for (int r = 0; r < 4; ++r) {
      float e = __expf(S[nt][r] - mx);
      if (nt == 6 && g == 3) e = 0.f;
      S[nt][r] = e;
      sum += e;
    }
  }
  sum += __shfl_xor(sum, 16);
  sum += __shfl_xor(sum, 32);
  float inv = 1.f / sum;
  short8 av[4];
  #pragma unroll
  for (int ks = 0; ks < 4; ++ks)
    av[ks] = *(const short8*)(&vb[((size_t)h * 16 + l15) * 128 + ks * 32 + g * 8]);
  f32x4 o = f32x4{0.f, 0.f, 0.f, 0.f};
  #pragma unroll
  for (int ks = 0; ks < 4; ++ks) {
    unsigned w0 = cvtpk(S[2 * ks][0], S[2 * ks][1]);
    unsigned w1 = cvtpk(S[2 * ks][2], S[2 * ks][3]);
    unsigned w2 = 0, w3 = 0;
    if (ks < 3) {
      w2 = cvtpk(S[2 * ks + 1][0], S[2 * ks + 1][1]);
      w3 = cvtpk(S[2 * ks + 1][2], S[2 * ks + 1][3]);
    }
    short8 pa = mk8(w0, w1, w2, w3);
    o = __builtin_amdgcn_mfma_f32_16x16x32_bf16(av[ks], pa, o, 0, 0, 0);
  }
  o[0] *= inv; o[1] *= inv; o[2] *= inv; o[3] *= inv;
  return o;
}

// ---------------- fused attention v4b (EXACT r12): register softmax/PV, batched loads ----------------
__global__ __launch_bounds__(256, 2) void k_att4(
    const float* __restrict__ query, const float* __restrict__ tab,
    const unsigned short* __restrict__ kp2, const unsigned short* __restrict__ vtp,
    const unsigned short* __restrict__ wq, const unsigned short* __restrict__ wop2,
    const float* __restrict__ in_b, const float* __restrict__ out_b,
    const float* __restrict__ ln_w, const float* __restrict__ ln_b,
    float* __restrict__ out) {
  __shared__ __align__(16) unsigned char smem[34816];
  int tid = threadIdx.x;
  int nw = blockIdx.x, part = blockIdx.y;
  int dg = nw >> 6, hg = (nw >> 3) & 7, wg = nw & 7;
  int wave = tid >> 6, lane = tid & 63, l15 = lane & 15, g = lane >> 4;
  unsigned char* wbase = smem + wave * 8704;
  unsigned short* qtile = (unsigned short*)wbase;   // [16][136] head-padded scaled Q
  unsigned short* sPq   = qtile + 2176;             // [16][136] qin staging
  int wid = part * 4 + wave;                        // [0,16)

  for (int c = lane; c < 544; c += 64)
    *(int4*)(wbase + c * 16) = int4{0, 0, 0, 0};
  asm volatile("s_waitcnt lgkmcnt(0)" ::: "memory");

  const float scale = 0.28867513459481287f;  // 1/sqrt(12), folded into q
  float biasq[6];
  #pragma unroll
  for (int nt = 0; nt < 6; ++nt) biasq[nt] = in_b[nt * 16 + l15];
  const unsigned short* kb = kp2 + (size_t)nw * 8 * 112 * 16;
  const unsigned short* vb = vtp + (size_t)nw * 8 * 16 * 128;

  for (int mt = wid; mt < 54; mt += 16) {
    for (int c = lane; c < 16 * 48; c += 64) {
      int row = c & 15, cop = c >> 4;
      int co = cop * 2;
      int l = mt * 16 + row;
      int ld = l / 144, lh = (l / 12) % 12, lw = l % 12;
      int d = dg * 6 + ld, h = hg * 12 + lh, w = wg * 12 + lw;
      size_t qoff = (((size_t)co * 24 + d) * 96 + h) * 96 + w;
      float v0 = query[qoff] + tab[d * 96 + co] + tab[2304 + h * 96 + co] + tab[11520 + w * 96 + co];
      float v1 = query[qoff + 221184] + tab[d * 96 + co + 1] + tab[2304 + h * 96 + co + 1] + tab[11520 + w * 96 + co + 1];
      *(unsigned*)(&sPq[row * 136 + co]) = (unsigned)f2bf(v0) | ((unsigned)f2bf(v1) << 16);
    }
    asm volatile("s_waitcnt lgkmcnt(0)" ::: "memory");
    {
      f32x4 QD[6];
      #pragma unroll
      for (int nt = 0; nt < 6; ++nt) QD[nt] = f32x4{0.f, 0.f, 0.f, 0.f};
      #pragma unroll
      for (int ks = 0; ks < 3; ++ks) {
        short8 a = *(const short8*)(&sPq[l15 * 136 + ks * 32 + g * 8]);
        #pragma unroll
        for (int nt = 0; nt < 6; ++nt) {
          short8 bw = *(const short8*)(&wq[(nt * 16 + l15) * 96 + ks * 32 + g * 8]);
          QD[nt] = __builtin_amdgcn_mfma_f32_16x16x32_bf16(a, bw, QD[nt], 0, 0, 0);
        }
      }
      #pragma unroll
      for (int nt = 0; nt < 6; ++nt) {
        int co = nt * 16 + l15;
        #pragma unroll
        for (int r = 0; r < 4; ++r) {
          float v = (QD[nt][r] + biasq[nt]) * scale;
          float v2 = __shfl_xor(v, 1);
          if (!(l15 & 1)) {
            int row = g * 4 + r;
            unsigned pk = (unsigned)f2bf(v) | ((unsigned)f2bf(v2) << 16);
            *(unsigned*)(&qtile[row * 136 + (co / 12) * 16 + co % 12]) = pk;
          }
        }
      }
    }
    asm volatile("s_waitcnt lgkmcnt(0)" ::: "memory");
    f32x4 R[6];
    #pragma unroll
    for (int nt = 0; nt < 6; ++nt) R[nt] = f32x4{0.f, 0.f, 0.f, 0.f};
    #pragma unroll
    for (int hp = 0; hp < 4; ++hp) {
      f32x4 oA = proc_head(qtile, kb, vb, 2 * hp, lane, l15, g);
      f32x4 oB = proc_head(qtile, kb, vb, 2 * hp + 1, lane, l15, g);
      short8 pb = mk8(cvtpk(oA[0], oA[1]), cvtpk(oA[2], oA[3]),
                      cvtpk(oB[0], oB[1]), cvtpk(oB[2], oB[3]));
      #pragma unroll
      for (int nt = 0; nt < 6; ++nt) {
        short8 aw = *(const short8*)(&wop2[(nt * 16 + l15) * 128 + hp * 32 + g * 8]);
        R[nt] = __builtin_amdgcn_mfma_f32_16x16x32_bf16(aw, pb, R[nt], 0, 0, 0);
      }
    }
    {
      int l = mt * 16 + l15;
      int ld = l / 144, lh = (l / 12) % 12, lw = l % 12;
      int d = dg * 6 + ld, h_ = hg * 12 + lh, w_ = wg * 12 + lw;
      size_t sp = ((size_t)d * 96 + h_) * 96 + w_;
      float s = 0.f, s2 = 0.f;
      #pragma unroll
      for (int nt = 0; nt < 6; ++nt) {
        #pragma unroll
        for (int r = 0; r < 4; ++r) {
          int co = nt * 16 + 4 * g + r;
          float v = R[nt][r] + out_b[co] + query[(size_t)co * 221184 + sp];
          R[nt][r] = v;
          s += v; s2 += v * v;
        }
      }
      s += __shfl_xor(s, 16); s2 += __shfl_xor(s2, 16);
      s += __shfl_xor(s, 32); s2 += __shfl_xor(s2, 32);
      float mu = s * (1.f / 96.f);
      float var = s2 * (1.f / 96.f) - mu * mu;
      float rstd = rsqrtf(var + 1e-5f);
      #pragma unroll
      for (int nt = 0; nt < 6; ++nt) {
        #pragma unroll
        for (int r = 0; r < 4; ++r) {
          int co = nt * 16 + 4 * g + r;
          out[(size_t)co * 221184 + sp] = (R[nt][r] - mu) * rstd * ln_w[co] + ln_b[co];
        }
      }
    }
  } // m-tiles
}

extern "C" void kernel_launch(void* const* d_in, const int* in_sizes, int n_in,
                              void* d_out, int out_size, void* d_ws, size_t ws_size,
                              hipStream_t stream) {
  const float* query = (const float*)d_in[0];
  const float* mem   = (const float*)d_in[1];
  const float* pos_w = (const float*)d_in[2];
  const float* l_w1  = (const float*)d_in[3];
  const float* l_b1  = (const float*)d_in[4];
  const float* l_w2  = (const float*)d_in[5];
  const float* l_b2  = (const float*)d_in[6];
  const float* g_w1  = (const float*)d_in[7];
  const float* g_b1  = (const float*)d_in[8];
  const float* g_w2  = (const float*)d_in[9];
  const float* g_b2  = (const float*)d_in[10];
  const float* in_w  = (const float*)d_in[11];
  const float* in_b  = (const float*)d_in[12];
  const float* out_w = (const float*)d_in[13];
  const float* out_b = (const float*)d_in[14];
  const float* ln_w  = (const float*)d_in[15];
  const float* ln_b  = (const float*)d_in[16];
  unsigned char* ws = (unsigned char*)d_ws;
  float* tab  = (float*)(ws + OFFB_TAB);
  float* gsum = (float*)(ws + OFFB_GSUM);
  float* glo  = (float*)(ws + OFFB_GLO);
  float* xm   = (float*)(ws + OFFB_XM);   // reused in-place as fre
  float* low  = (float*)(ws + OFFB_LOW);
  unsigned short* wq   = (unsigned short*)(ws + OFFB_WQ);
  unsigned short* wk   = (unsigned short*)(ws + OFFB_WK);
  unsigned short* wv   = (unsigned short*)(ws + OFFB_WV);
  unsigned short* kp2  = (unsigned short*)(ws + OFFB_KP);
  unsigned short* vtp  = (unsigned short*)(ws + OFFB_VT);
  unsigned short* wop2 = (unsigned short*)(ws + OFFB_WOP);
  unsigned short* wg1  = (unsigned short*)(ws + OFFB_WG1);
  unsigned short* wg2  = (unsigned short*)(ws + OFFB_WG2);

  k_prep<<<1182, 256, 0, stream>>>(pos_w, tab, in_w, out_w, l_w1, l_w2,
                                   wq, wk, wv, wop2, wg1, wg2,
                                   gsum, ws + ZERO_OFF);
  k_wav<<<576, 256, 0, stream>>>(mem, xm, low, gsum);
  k_glo<<<1, 128, 0, stream>>>(gsum, g_w1, g_b1, g_w2, g_b2, glo);
  k_gate2<<<256, 256, 0, stream>>>(xm, low, wg1, wg2, l_b1, l_b2, glo, xm);
  k_kv2<<<256, 256, 0, stream>>>(xm, tab, wk, wv, in_b, kp2, vtp);
  k_att4<<<dim3(256, 4), 256, 0, stream>>>(query, tab, kp2, vtp, wq, wop2, in_b, out_b,
                                           ln_w, ln_b, (float*)d_out);
}